// Round 6
// baseline (280.274 us; speedup 1.0000x reference)
//
#include <hip/hip_runtime.h>
#include <hip/hip_bf16.h>
#include <cstdint>

// Problem constants
#define S_FRAMES 128
#define HW       50176            // 224*224
#define NGRP     12544            // HW/4 float4 groups per frame
#define GDIM     48
#define VWORDS   3456             // 48^3 / 32 bits
#define NBINS    4096
#define CAP      512
#define KSEL     16

// fallback greedy decomposition
#define GBLK     16               // blocks
#define FPB      8                // frames per block
#define GW       4                // occ words per thread (tid + k*1024)

// compact greedy
#define UWC      512u             // compact stride (words) per frame
#define UCAP_BITS 16384u          // max compact bits (fits 64 regs * 8 slices)
#define SLW      64               // max words per slice

// workspace layout (in 32-bit words)
#define OCCA_OFF  0u                          // 128 * 3456 words (part 0 bitmaps)
#define OCCB_OFF  (128u*3456u)                // 442368: part 1 bitmaps
#define SLOT_OFF  (2u*128u*3456u)             // 884736: 16 blocks x 32 words (own lines)
#define MM_OFF    (SLOT_OFF + 512u)           // 64 slots x 16 words (64B each)
#define PCT_OFF   (MM_OFF + 64u*16u)          // 128 floats
#define FLAG_OFF  (PCT_OFF + 128u)            // 1=fallback, 2=compact
#define UW_OFF    (FLAG_OFF + 1u)             // compact words per frame
#define UNI_OFF   (FLAG_OFF + 16u)            // union bitmap, 3456 words
#define CMP_OFF   (UNI_OFF + VWORDS)          // 128 x 512 compact bitmaps
#define ZERO_OFF  SLOT_OFF
#define ZERO_WORDS (PCT_OFF - SLOT_OFF)       // slots + mm slots

__device__ __forceinline__ unsigned fkey(float f) {
    unsigned u = __float_as_uint(f);
    return (u & 0x80000000u) ? ~u : (u | 0x80000000u);
}
__device__ __forceinline__ float funkey(unsigned k) {
    unsigned u = (k & 0x80000000u) ? (k & 0x7fffffffu) : ~k;
    return __uint_as_float(u);
}

// ---------------------------------------------------------------------------
// Pass A: exact per-frame median (jnp.quantile 0.5 linear) via histogram select
// ---------------------------------------------------------------------------
__global__ __launch_bounds__(1024) void pct_kernel(const float* __restrict__ conf,
                                                   float* __restrict__ pct) {
    const int s = blockIdx.x;
    const int tid = threadIdx.x;
    const int lane = tid & 63, wid = tid >> 6;
    const float4* c4 = (const float4*)(conf + (size_t)s * HW);

    __shared__ unsigned hist[NBINS];
    __shared__ unsigned wtot[16];
    __shared__ unsigned woff[16];
    __shared__ float    list[CAP];
    __shared__ unsigned cnt;
    __shared__ int      rbin[2];
    __shared__ unsigned rcum[2];
    __shared__ float    ab[2];

    for (int b = tid; b < NBINS; b += 1024) hist[b] = 0;
    if (tid == 0) cnt = 0;
    __syncthreads();

    for (int g = tid; g < NGRP; g += 1024) {
        float4 v = c4[g];
        int b0 = min(max((int)(v.x * 4096.0f), 0), NBINS - 1);
        int b1 = min(max((int)(v.y * 4096.0f), 0), NBINS - 1);
        int b2 = min(max((int)(v.z * 4096.0f), 0), NBINS - 1);
        int b3 = min(max((int)(v.w * 4096.0f), 0), NBINS - 1);
        atomicAdd(&hist[b0], 1u); atomicAdd(&hist[b1], 1u);
        atomicAdd(&hist[b2], 1u); atomicAdd(&hist[b3], 1u);
    }
    __syncthreads();

    unsigned chunk = hist[tid * 4] + hist[tid * 4 + 1] + hist[tid * 4 + 2] + hist[tid * 4 + 3];
    unsigned x = chunk;
#pragma unroll
    for (int m = 1; m < 64; m <<= 1) {
        unsigned y = (unsigned)__shfl_up((int)x, m);
        if (lane >= m) x += y;
    }
    if (lane == 63) wtot[wid] = x;
    __syncthreads();
    if (tid < 16) {
        unsigned acc = 0;
        for (int w = 0; w < tid; w++) acc += wtot[w];
        woff[tid] = acc;
    }
    __syncthreads();
    unsigned excl = x - chunk + woff[wid];

    const unsigned R0 = 25087u, R1 = 25088u;  // 0.5*(50176-1) = 25087.5
#pragma unroll
    for (int r = 0; r < 2; r++) {
        unsigned rr = r ? R1 : R0;
        if (rr >= excl && rr < excl + chunk) {
            unsigned cum = excl;
            for (int j = 0; j < 4; j++) {
                unsigned h = hist[tid * 4 + j];
                if (rr < cum + h) { rbin[r] = tid * 4 + j; rcum[r] = cum; break; }
                cum += h;
            }
        }
    }
    __syncthreads();

    const int blo = rbin[0], bhi = rbin[1];
    const unsigned cumLo = rcum[0];

    for (int g = tid; g < NGRP; g += 1024) {
        float4 v = c4[g];
        float vv[4] = {v.x, v.y, v.z, v.w};
#pragma unroll
        for (int j = 0; j < 4; j++) {
            int b = min(max((int)(vv[j] * 4096.0f), 0), NBINS - 1);
            if (b >= blo && b <= bhi) {
                unsigned pos = atomicAdd(&cnt, 1u);
                if (pos < CAP) list[pos] = vv[j];
            }
        }
    }
    __syncthreads();

    const int n = (int)min(cnt, (unsigned)CAP);
    const int r0 = (int)(R0 - cumLo), r1 = (int)(R1 - cumLo);
    for (int e = tid; e < n; e += 1024) {
        float xx = list[e];
        int rank = 0;
        for (int j = 0; j < n; j++) {
            float y = list[j];
            rank += (y < xx) || (y == xx && j < e);   // stable rank
        }
        if (rank == r0) ab[0] = xx;
        if (rank == r1) ab[1] = xx;
    }
    __syncthreads();
    if (tid == 0) pct[s] = 0.5f * ab[0] + 0.5f * ab[1];
}

// ---------------------------------------------------------------------------
// Pass B: global min/max over valid points. grid (49,128) x 256, 4 pts/thread.
// ---------------------------------------------------------------------------
__global__ __launch_bounds__(256) void minmax_kernel(const float* __restrict__ wp,
                                                     const float* __restrict__ conf,
                                                     const float* __restrict__ pct,
                                                     unsigned* __restrict__ ws) {
    const int s = blockIdx.y;
    const int tid = threadIdx.x;
    const int gidx = blockIdx.x * 256 + tid;        // [0, 12544)
    const float pc = pct[s];
    const size_t base = (size_t)s * HW;

    const float4 cf = ((const float4*)(conf + base))[gidx];
    const float4* wp4 = (const float4*)(wp + base * 3) + (size_t)gidx * 3;
    const float4 a = wp4[0], b = wp4[1], d = wp4[2];

    const float BIG = 3.402823466e38f;
    float mnx = BIG, mny = BIG, mnz = BIG;
    float mxx = -BIG, mxy = -BIG, mxz = -BIG;

    float px[4] = {a.x, a.w, b.z, d.y};
    float py[4] = {a.y, b.x, b.w, d.z};
    float pz[4] = {a.z, b.y, d.x, d.w};
    float cc[4] = {cf.x, cf.y, cf.z, cf.w};
#pragma unroll
    for (int j = 0; j < 4; j++) {
        bool v = (cc[j] > 0.1f) && (cc[j] >= pc);
        float x = v ? px[j] : BIG, y = v ? py[j] : BIG, z = v ? pz[j] : BIG;
        mnx = fminf(mnx, x); mny = fminf(mny, y); mnz = fminf(mnz, z);
        x = v ? px[j] : -BIG; y = v ? py[j] : -BIG; z = v ? pz[j] : -BIG;
        mxx = fmaxf(mxx, x); mxy = fmaxf(mxy, y); mxz = fmaxf(mxz, z);
    }
#pragma unroll
    for (int m = 32; m >= 1; m >>= 1) {
        mnx = fminf(mnx, __shfl_xor(mnx, m)); mny = fminf(mny, __shfl_xor(mny, m));
        mnz = fminf(mnz, __shfl_xor(mnz, m));
        mxx = fmaxf(mxx, __shfl_xor(mxx, m)); mxy = fmaxf(mxy, __shfl_xor(mxy, m));
        mxz = fmaxf(mxz, __shfl_xor(mxz, m));
    }
    __shared__ float red[4][6];
    if ((tid & 63) == 0) {
        int w = tid >> 6;
        red[w][0] = mnx; red[w][1] = mny; red[w][2] = mnz;
        red[w][3] = mxx; red[w][4] = mxy; red[w][5] = mxz;
    }
    __syncthreads();
    if (tid == 0) {
        float r0 = red[0][0], r1 = red[0][1], r2 = red[0][2];
        float r3 = red[0][3], r4 = red[0][4], r5 = red[0][5];
        for (int w = 1; w < 4; w++) {
            r0 = fminf(r0, red[w][0]); r1 = fminf(r1, red[w][1]); r2 = fminf(r2, red[w][2]);
            r3 = fmaxf(r3, red[w][3]); r4 = fmaxf(r4, red[w][4]); r5 = fmaxf(r5, red[w][5]);
        }
        unsigned* slot = ws + MM_OFF + (unsigned)((blockIdx.x + blockIdx.y * 49) & 63) * 16;
        atomicMax(slot + 0, fkey(-r0));   // min x  (as max of key(-x))
        atomicMax(slot + 1, fkey(-r1));
        atomicMax(slot + 2, fkey(-r2));
        atomicMax(slot + 3, fkey(r3));    // max x
        atomicMax(slot + 4, fkey(r4));
        atomicMax(slot + 5, fkey(r5));
    }
}

// ---------------------------------------------------------------------------
// Pass C: per-frame voxel occupancy. grid 256 (2 blocks/frame) x 512 threads.
// ---------------------------------------------------------------------------
__global__ __launch_bounds__(512) void voxel_kernel(const float* __restrict__ wp,
                                                    const float* __restrict__ conf,
                                                    const float* __restrict__ pct,
                                                    unsigned* __restrict__ ws) {
    const int s = blockIdx.x >> 1;
    const int part = blockIdx.x & 1;
    const int tid = threadIdx.x;

    __shared__ unsigned bm[VWORDS];
    __shared__ float prm[4];  // pmx,pmy,pmz,vs
    for (int w = tid; w < VWORDS; w += 512) bm[w] = 0;

    if (tid < 64) {
        const unsigned* sl = ws + MM_OFF + (unsigned)tid * 16;
        unsigned k0 = sl[0], k1 = sl[1], k2 = sl[2], k3 = sl[3], k4 = sl[4], k5 = sl[5];
#pragma unroll
        for (int m = 32; m >= 1; m >>= 1) {
            k0 = max(k0, (unsigned)__shfl_xor((int)k0, m));
            k1 = max(k1, (unsigned)__shfl_xor((int)k1, m));
            k2 = max(k2, (unsigned)__shfl_xor((int)k2, m));
            k3 = max(k3, (unsigned)__shfl_xor((int)k3, m));
            k4 = max(k4, (unsigned)__shfl_xor((int)k4, m));
            k5 = max(k5, (unsigned)__shfl_xor((int)k5, m));
        }
        if (tid == 0) {
            float p0 = -funkey(k0), p1 = -funkey(k1), p2 = -funkey(k2);
            float d0 = funkey(k3) - p0, d1 = funkey(k4) - p1, d2 = funkey(k5) - p2;
            prm[0] = p0; prm[1] = p1; prm[2] = p2;
            prm[3] = fminf(d0, fminf(d1, d2)) / 20.0f;   // VOXEL_LAMBDA
        }
    }
    __syncthreads();

    const float pc = pct[s];
    const float pmx = prm[0], pmy = prm[1], pmz = prm[2], vs = prm[3];
    const size_t base = (size_t)s * HW;
    const float4* c4 = (const float4*)(conf + base);
    const float4* w4 = (const float4*)(wp + base * 3);

#pragma unroll 1
    for (int k = 0; k < 13; k++) {
        int gl = k * 512 + tid;                        // local group in half
        if (gl >= 6272) break;
        int g = part * 6272 + gl;
        float4 cf = c4[g];
        const float4* wg = w4 + (size_t)g * 3;
        float4 a = wg[0], b = wg[1], d = wg[2];
        float px[4] = {a.x, a.w, b.z, d.y};
        float py[4] = {a.y, b.x, b.w, d.z};
        float pz[4] = {a.z, b.y, d.x, d.w};
        float cc[4] = {cf.x, cf.y, cf.z, cf.w};
#pragma unroll
        for (int j = 0; j < 4; j++) {
            if (cc[j] > 0.1f && cc[j] >= pc) {
                int ix = min(max((int)floorf((px[j] - pmx) / vs), 0), GDIM - 1);
                int iy = min(max((int)floorf((py[j] - pmy) / vs), 0), GDIM - 1);
                int iz = min(max((int)floorf((pz[j] - pmz) / vs), 0), GDIM - 1);
                int vid = (ix * GDIM + iy) * GDIM + iz;
                atomicOr(&bm[vid >> 5], 1u << (vid & 31));
            }
        }
    }
    __syncthreads();

    unsigned* occ = ws + (part ? OCCB_OFF : OCCA_OFF) + (unsigned)s * VWORDS;
    for (int w = tid; w < VWORDS; w += 512) occ[w] = bm[w];
}

// ---------------------------------------------------------------------------
// Union of all frame bitmaps. grid 14 x 256 (word-parallel, lane-coalesced).
// ---------------------------------------------------------------------------
__global__ __launch_bounds__(256) void union_kernel(unsigned* __restrict__ ws) {
    int w = blockIdx.x * 256 + threadIdx.x;
    if (w >= VWORDS) return;
    const unsigned* pA = ws + OCCA_OFF;
    const unsigned* pB = ws + OCCB_OFF;
    unsigned u = 0;
#pragma unroll 4
    for (int f = 0; f < S_FRAMES; f++)
        u |= pA[(unsigned)f * VWORDS + w] | pB[(unsigned)f * VWORDS + w];
    ws[UNI_OFF + w] = u;
}

// ---------------------------------------------------------------------------
// Remap each frame's bitmap into compact-id space (rank within union).
// grid 128 x 256; each block redundantly scans the union for base[] (exact).
// ---------------------------------------------------------------------------
__global__ __launch_bounds__(256) void remap_kernel(unsigned* __restrict__ ws) {
    const int f = blockIdx.x;
    const int tid = threadIdx.x;
    const int lane = tid & 63, wid = tid >> 6;

    __shared__ unsigned uni[VWORDS];
    __shared__ unsigned short basew[VWORDS];
    __shared__ unsigned cbm[UWC];
    __shared__ unsigned wtot[4];
    __shared__ unsigned Ush;

    for (int w = tid; w < VWORDS; w += 256) uni[w] = ws[UNI_OFF + w];
    for (int w = tid; w < (int)UWC; w += 256) cbm[w] = 0;
    __syncthreads();

    // popc prefix scan: 14 words/thread (14*256 >= 3456)
    const int w0 = tid * 14;
    unsigned chunk = 0;
#pragma unroll
    for (int j = 0; j < 14; j++) { int w = w0 + j; if (w < VWORDS) chunk += __popc(uni[w]); }
    unsigned x = chunk;
#pragma unroll
    for (int m = 1; m < 64; m <<= 1) {
        unsigned y = (unsigned)__shfl_up((int)x, m);
        if (lane >= m) x += y;
    }
    if (lane == 63) wtot[wid] = x;
    __syncthreads();
    unsigned woffv = 0;
    for (int wv = 0; wv < 4; wv++) if (wv < wid) woffv += wtot[wv];
    unsigned running = x - chunk + woffv;
#pragma unroll
    for (int j = 0; j < 14; j++) {
        int w = w0 + j;
        if (w < VWORDS) { basew[w] = (unsigned short)running; running += __popc(uni[w]); }
    }
    if (tid == 255) Ush = running;
    __syncthreads();
    const unsigned U = Ush;
    if (f == 0 && tid == 0) { ws[FLAG_OFF] = (U <= UCAP_BITS) ? 2u : 1u; ws[UW_OFF] = (U + 31) >> 5; }
    if (U > UCAP_BITS) return;   // fallback path will run

    const unsigned* pA = ws + OCCA_OFF + (unsigned)f * VWORDS;
    const unsigned* pB = ws + OCCB_OFF + (unsigned)f * VWORDS;
    for (int w = tid; w < VWORDS; w += 256) {
        unsigned v = pA[w] | pB[w];
        if (!v) continue;
        unsigned uw = uni[w], b0 = basew[w];
        while (v) {
            int b = __ffs(v) - 1; v &= v - 1;
            unsigned cid = b0 + (unsigned)__popc(uw & ((1u << b) - 1u));
            atomicOr(&cbm[cid >> 5], 1u << (cid & 31));
        }
    }
    __syncthreads();
    const unsigned UW = (U + 31) >> 5;
    for (unsigned w = tid; w < UW; w += 256) ws[CMP_OFF + (unsigned)f * UWC + w] = cbm[w];
}

// ---------------------------------------------------------------------------
// Compact greedy: ONE block x 1024 threads. thread = (frame f=tid>>3, slice
// sl=tid&7); occ words in registers, covered bitmap in LDS. Owners of `best`
// fold cov directly (disjoint words). 3 barriers/iter, zero global sync.
// ---------------------------------------------------------------------------
__global__ __launch_bounds__(1024) void greedy1_kernel(unsigned* __restrict__ ws,
                                                       float* __restrict__ out) {
    if (ws[FLAG_OFF] != 2u) return;
    const int tid = threadIdx.x;
    const int f = tid >> 3, sl = tid & 7;
    const unsigned UW = ws[UW_OFF];
    const int sw = (int)((UW + 7) >> 3);          // words per slice, <= 64
    const int wbase = sl * sw;

    __shared__ unsigned cov[UWC];
    __shared__ int gains[S_FRAMES];
    __shared__ unsigned bestsh;

    unsigned occw[SLW];
    const unsigned* cmp = ws + CMP_OFF + (unsigned)f * UWC;
#pragma unroll
    for (int j = 0; j < SLW; j++) {
        int w = wbase + j;
        occw[j] = (j < sw && w < (int)UW) ? cmp[w] : 0u;
    }
    for (int w = tid; w < (int)UWC; w += 1024) cov[w] = 0u;

    bool selF = false;
    int best = -1;
    __syncthreads();

    for (int it = 0; it < KSEL; it++) {
        if (best >= 0 && f == best) {             // owners fold cov (disjoint w)
#pragma unroll
            for (int j = 0; j < SLW; j++) {
                int w = wbase + j;
                if (j < sw && w < (int)UW) cov[w] |= occw[j];
            }
        }
        __syncthreads();                          // B1: cov updated
        int g = 0;
#pragma unroll
        for (int j = 0; j < SLW; j++) {
            int w = wbase + j;
            if (j < sw && w < (int)UW) g += __popc(occw[j] & ~cov[w]);
        }
        g += __shfl_xor(g, 1); g += __shfl_xor(g, 2); g += __shfl_xor(g, 4);
        if (sl == 0) gains[f] = selF ? -1 : g;
        __syncthreads();                          // B2: gains ready
        if (tid < 64) {
            int g1 = gains[tid], g2 = gains[tid + 64];
            // key: max gain, then smallest s (jnp.argmax first-max tie-break)
            unsigned k1 = (g1 < 0) ? 0u : (((unsigned)g1 << 7) | (unsigned)(127 - tid));
            unsigned k2 = (g2 < 0) ? 0u : (((unsigned)g2 << 7) | (unsigned)(63 - tid));
            unsigned k = max(k1, k2);
#pragma unroll
            for (int m = 32; m >= 1; m >>= 1) k = max(k, (unsigned)__shfl_xor((int)k, m));
            if (tid == 0) {
                bestsh = k;
                out[it] = (float)(127 - (int)(k & 127u));
                out[KSEL + it] = (float)(k >> 7);
            }
        }
        __syncthreads();                          // B3: best visible
        best = 127 - (int)(bestsh & 127u);
        if (f == best) selF = true;
    }

    // total coverage: fold last best, popc over cov (f==0 group covers all w)
    if (f == best) {
#pragma unroll
        for (int j = 0; j < SLW; j++) {
            int w = wbase + j;
            if (j < sw && w < (int)UW) cov[w] |= occw[j];
        }
    }
    __syncthreads();
    if (f == 0) {
        int t = 0;
#pragma unroll
        for (int j = 0; j < SLW; j++) {
            int w = wbase + j;
            if (j < sw && w < (int)UW) t += __popc(cov[w]);
        }
        t += __shfl_xor(t, 1); t += __shfl_xor(t, 2); t += __shfl_xor(t, 4);
        if (sl == 0) out[2 * KSEL] = (float)t;
    }
}

// ---------------------------------------------------------------------------
// Fallback greedy (only if U > UCAP_BITS): 16 blocks x 1024, slot all-gather.
// ---------------------------------------------------------------------------
__global__ __launch_bounds__(1024) void greedy_kernel(unsigned* __restrict__ ws,
                                                      float* __restrict__ out) {
    if (ws[FLAG_OFF] == 2u) return;
    const int b = blockIdx.x;
    const int tid = threadIdx.x;
    const int lane = tid & 63, wid = tid >> 6;
    const unsigned* pA = ws + OCCA_OFF;
    const unsigned* pB = ws + OCCB_OFF;
    unsigned* slots = ws + SLOT_OFF;         // slot(b,it) = b*32 + it

    unsigned occ[FPB][GW], cov[GW];
#pragma unroll
    for (int k = 0; k < GW; k++) cov[k] = 0u;
#pragma unroll
    for (int j = 0; j < FPB; j++) {
        unsigned f = (unsigned)(b * FPB + j);
#pragma unroll
        for (int k = 0; k < GW; k++) {
            int w = tid + k * 1024;
            occ[j][k] = (w < VWORDS) ? (pA[f * VWORDS + w] | pB[f * VWORDS + w]) : 0u;
        }
    }

    __shared__ int part[16][FPB];
    __shared__ unsigned bbc;
    unsigned selMask = 0;
    int best = -1;

    for (int it = 0; it < KSEL; it++) {
        if (best >= 0) {
            const unsigned* bA = pA + (unsigned)best * VWORDS;
            const unsigned* bB = pB + (unsigned)best * VWORDS;
#pragma unroll
            for (int k = 0; k < GW; k++) {
                int w = tid + k * 1024;
                if (w < VWORDS) cov[k] |= bA[w] | bB[w];
            }
        }
#pragma unroll
        for (int j = 0; j < FPB; j++) {
            int g = 0;
#pragma unroll
            for (int k = 0; k < GW; k++) g += __popc(occ[j][k] & ~cov[k]);
#pragma unroll
            for (int m = 32; m >= 1; m >>= 1) g += __shfl_xor(g, m);
            if (lane == 0) part[wid][j] = g;
        }
        __syncthreads();
        if (wid == 0) {
            unsigned key = 0;
            if (lane < FPB) {
                int g = 0;
#pragma unroll
                for (int w = 0; w < 16; w++) g += part[w][lane];
                int f = b * FPB + lane;
                key = ((selMask >> lane) & 1u) ? 0u
                    : (((unsigned)g << 7) | (unsigned)(127 - f));
            }
#pragma unroll
            for (int m = 4; m >= 1; m >>= 1) key = max(key, (unsigned)__shfl_xor((int)key, m));
            if (lane == 0)
                __hip_atomic_store(&slots[b * 32 + it], key | 0x80000000u,
                                   __ATOMIC_RELAXED, __HIP_MEMORY_SCOPE_AGENT);
            unsigned p = 0;
            if (lane < GBLK) {
                unsigned v;
                do {
                    v = __hip_atomic_load(&slots[lane * 32 + it],
                                          __ATOMIC_RELAXED, __HIP_MEMORY_SCOPE_AGENT);
                } while (!(v & 0x80000000u));
                p = v & 0x7fffffffu;
            }
#pragma unroll
            for (int m = 8; m >= 1; m >>= 1) p = max(p, (unsigned)__shfl_xor((int)p, m));
            if (lane == 0) bbc = p;
        }
        __syncthreads();
        unsigned kk = bbc;
        best = 127 - (int)(kk & 127u);
        if (best >= b * FPB && best < (b + 1) * FPB) selMask |= 1u << (best - b * FPB);
        if (b == 0 && tid == 0) {
            out[it] = (float)best;
            out[KSEL + it] = (float)(kk >> 7);
        }
        __syncthreads();
    }

    if (b == 0) {
        const unsigned* bA = pA + (unsigned)best * VWORDS;
        const unsigned* bB = pB + (unsigned)best * VWORDS;
        int t = 0;
#pragma unroll
        for (int k = 0; k < GW; k++) {
            int w = tid + k * 1024;
            if (w < VWORDS) t += __popc(cov[k] | bA[w] | bB[w]);
        }
#pragma unroll
        for (int m = 32; m >= 1; m >>= 1) t += __shfl_xor(t, m);
        if (lane == 0) part[wid][0] = t;
        __syncthreads();
        if (tid == 0) {
            int tt = 0;
            for (int w = 0; w < 16; w++) tt += part[w][0];
            out[2 * KSEL] = (float)tt;
        }
    }
}

extern "C" void kernel_launch(void* const* d_in, const int* in_sizes, int n_in,
                              void* d_out, int out_size, void* d_ws, size_t ws_size,
                              hipStream_t stream) {
    const float* wp   = (const float*)d_in[2];  // world_points [1,S,H,W,3]
    const float* conf = (const float*)d_in[3];  // world_points_conf [1,S,H,W]
    float* out = (float*)d_out;
    unsigned* ws = (unsigned*)d_ws;

    // zero only the control region: key slots + minmax slots
    hipMemsetAsync(ws + ZERO_OFF, 0, (size_t)ZERO_WORDS * 4, stream);

    float* pct = (float*)(ws + PCT_OFF);
    pct_kernel<<<128, 1024, 0, stream>>>(conf, pct);
    minmax_kernel<<<dim3(49, 128), 256, 0, stream>>>(wp, conf, pct, ws);
    voxel_kernel<<<256, 512, 0, stream>>>(wp, conf, pct, ws);
    union_kernel<<<14, 256, 0, stream>>>(ws);
    remap_kernel<<<128, 256, 0, stream>>>(ws);
    greedy1_kernel<<<1, 1024, 0, stream>>>(ws, out);
    greedy_kernel<<<GBLK, 1024, 0, stream>>>(ws, out);
}

// Round 7
// 265.800 us; speedup vs baseline: 1.0545x; 1.0545x over previous
//
#include <hip/hip_runtime.h>
#include <hip/hip_bf16.h>
#include <cstdint>

// Problem constants
#define S_FRAMES 128
#define HW       50176            // 224*224
#define NGRP     12544            // HW/4 float4 groups per frame
#define GDIM     48
#define VWORDS   3456             // 48^3 / 32 bits
#define NBINS    4096
#define CAP      512
#define KSEL     16

// fallback greedy decomposition
#define GBLK     16               // blocks
#define FPB      8                // frames per block
#define GW       4                // occ words per thread (tid + k*1024)

// compact greedy
#define UWC      512u             // compact stride (words) per frame, zero-padded
#define UCAP_BITS 16384u          // max compact bits handled by greedy1

// workspace layout (in 32-bit words)
#define OCCA_OFF  0u                          // 128 * 3456 words (part 0 bitmaps)
#define OCCB_OFF  (128u*3456u)                // 442368: part 1 bitmaps
#define SLOT_OFF  (2u*128u*3456u)             // 884736: 16 blocks x 32 words (own lines)
#define MM_OFF    (SLOT_OFF + 512u)           // 64 slots x 16 words (64B each)
#define PCT_OFF   (MM_OFF + 64u*16u)          // 128 floats
#define FLAG_OFF  (PCT_OFF + 128u)            // 1=fallback, 2=compact
#define UW_OFF    (FLAG_OFF + 1u)             // compact words per frame
#define UNI_OFF   (FLAG_OFF + 16u)            // union bitmap, 3456 words
#define CMP_OFF   (UNI_OFF + VWORDS)          // 128 x 512 compact bitmaps (16B aligned)
#define ZERO_OFF  SLOT_OFF
#define ZERO_WORDS (PCT_OFF - SLOT_OFF)       // slots + mm slots

__device__ __forceinline__ unsigned fkey(float f) {
    unsigned u = __float_as_uint(f);
    return (u & 0x80000000u) ? ~u : (u | 0x80000000u);
}
__device__ __forceinline__ float funkey(unsigned k) {
    unsigned u = (k & 0x80000000u) ? (k & 0x7fffffffu) : ~k;
    return __uint_as_float(u);
}

// ---------------------------------------------------------------------------
// Pass A: exact per-frame median (jnp.quantile 0.5 linear) via histogram select
// ---------------------------------------------------------------------------
__global__ __launch_bounds__(1024) void pct_kernel(const float* __restrict__ conf,
                                                   float* __restrict__ pct) {
    const int s = blockIdx.x;
    const int tid = threadIdx.x;
    const int lane = tid & 63, wid = tid >> 6;
    const float4* c4 = (const float4*)(conf + (size_t)s * HW);

    __shared__ unsigned hist[NBINS];
    __shared__ unsigned wtot[16];
    __shared__ unsigned woff[16];
    __shared__ float    list[CAP];
    __shared__ unsigned cnt;
    __shared__ int      rbin[2];
    __shared__ unsigned rcum[2];
    __shared__ float    ab[2];

    for (int b = tid; b < NBINS; b += 1024) hist[b] = 0;
    if (tid == 0) cnt = 0;
    __syncthreads();

    for (int g = tid; g < NGRP; g += 1024) {
        float4 v = c4[g];
        int b0 = min(max((int)(v.x * 4096.0f), 0), NBINS - 1);
        int b1 = min(max((int)(v.y * 4096.0f), 0), NBINS - 1);
        int b2 = min(max((int)(v.z * 4096.0f), 0), NBINS - 1);
        int b3 = min(max((int)(v.w * 4096.0f), 0), NBINS - 1);
        atomicAdd(&hist[b0], 1u); atomicAdd(&hist[b1], 1u);
        atomicAdd(&hist[b2], 1u); atomicAdd(&hist[b3], 1u);
    }
    __syncthreads();

    unsigned chunk = hist[tid * 4] + hist[tid * 4 + 1] + hist[tid * 4 + 2] + hist[tid * 4 + 3];
    unsigned x = chunk;
#pragma unroll
    for (int m = 1; m < 64; m <<= 1) {
        unsigned y = (unsigned)__shfl_up((int)x, m);
        if (lane >= m) x += y;
    }
    if (lane == 63) wtot[wid] = x;
    __syncthreads();
    if (tid < 16) {
        unsigned acc = 0;
        for (int w = 0; w < tid; w++) acc += wtot[w];
        woff[tid] = acc;
    }
    __syncthreads();
    unsigned excl = x - chunk + woff[wid];

    const unsigned R0 = 25087u, R1 = 25088u;  // 0.5*(50176-1) = 25087.5
#pragma unroll
    for (int r = 0; r < 2; r++) {
        unsigned rr = r ? R1 : R0;
        if (rr >= excl && rr < excl + chunk) {
            unsigned cum = excl;
            for (int j = 0; j < 4; j++) {
                unsigned h = hist[tid * 4 + j];
                if (rr < cum + h) { rbin[r] = tid * 4 + j; rcum[r] = cum; break; }
                cum += h;
            }
        }
    }
    __syncthreads();

    const int blo = rbin[0], bhi = rbin[1];
    const unsigned cumLo = rcum[0];

    for (int g = tid; g < NGRP; g += 1024) {
        float4 v = c4[g];
        float vv[4] = {v.x, v.y, v.z, v.w};
#pragma unroll
        for (int j = 0; j < 4; j++) {
            int b = min(max((int)(vv[j] * 4096.0f), 0), NBINS - 1);
            if (b >= blo && b <= bhi) {
                unsigned pos = atomicAdd(&cnt, 1u);
                if (pos < CAP) list[pos] = vv[j];
            }
        }
    }
    __syncthreads();

    const int n = (int)min(cnt, (unsigned)CAP);
    const int r0 = (int)(R0 - cumLo), r1 = (int)(R1 - cumLo);
    for (int e = tid; e < n; e += 1024) {
        float xx = list[e];
        int rank = 0;
        for (int j = 0; j < n; j++) {
            float y = list[j];
            rank += (y < xx) || (y == xx && j < e);   // stable rank
        }
        if (rank == r0) ab[0] = xx;
        if (rank == r1) ab[1] = xx;
    }
    __syncthreads();
    if (tid == 0) pct[s] = 0.5f * ab[0] + 0.5f * ab[1];
}

// ---------------------------------------------------------------------------
// Pass B: global min/max over valid points. grid (49,128) x 256, 4 pts/thread.
// ---------------------------------------------------------------------------
__global__ __launch_bounds__(256) void minmax_kernel(const float* __restrict__ wp,
                                                     const float* __restrict__ conf,
                                                     const float* __restrict__ pct,
                                                     unsigned* __restrict__ ws) {
    const int s = blockIdx.y;
    const int tid = threadIdx.x;
    const int gidx = blockIdx.x * 256 + tid;        // [0, 12544)
    const float pc = pct[s];
    const size_t base = (size_t)s * HW;

    const float4 cf = ((const float4*)(conf + base))[gidx];
    const float4* wp4 = (const float4*)(wp + base * 3) + (size_t)gidx * 3;
    const float4 a = wp4[0], b = wp4[1], d = wp4[2];

    const float BIG = 3.402823466e38f;
    float mnx = BIG, mny = BIG, mnz = BIG;
    float mxx = -BIG, mxy = -BIG, mxz = -BIG;

    float px[4] = {a.x, a.w, b.z, d.y};
    float py[4] = {a.y, b.x, b.w, d.z};
    float pz[4] = {a.z, b.y, d.x, d.w};
    float cc[4] = {cf.x, cf.y, cf.z, cf.w};
#pragma unroll
    for (int j = 0; j < 4; j++) {
        bool v = (cc[j] > 0.1f) && (cc[j] >= pc);
        float x = v ? px[j] : BIG, y = v ? py[j] : BIG, z = v ? pz[j] : BIG;
        mnx = fminf(mnx, x); mny = fminf(mny, y); mnz = fminf(mnz, z);
        x = v ? px[j] : -BIG; y = v ? py[j] : -BIG; z = v ? pz[j] : -BIG;
        mxx = fmaxf(mxx, x); mxy = fmaxf(mxy, y); mxz = fmaxf(mxz, z);
    }
#pragma unroll
    for (int m = 32; m >= 1; m >>= 1) {
        mnx = fminf(mnx, __shfl_xor(mnx, m)); mny = fminf(mny, __shfl_xor(mny, m));
        mnz = fminf(mnz, __shfl_xor(mnz, m));
        mxx = fmaxf(mxx, __shfl_xor(mxx, m)); mxy = fmaxf(mxy, __shfl_xor(mxy, m));
        mxz = fmaxf(mxz, __shfl_xor(mxz, m));
    }
    __shared__ float red[4][6];
    if ((tid & 63) == 0) {
        int w = tid >> 6;
        red[w][0] = mnx; red[w][1] = mny; red[w][2] = mnz;
        red[w][3] = mxx; red[w][4] = mxy; red[w][5] = mxz;
    }
    __syncthreads();
    if (tid == 0) {
        float r0 = red[0][0], r1 = red[0][1], r2 = red[0][2];
        float r3 = red[0][3], r4 = red[0][4], r5 = red[0][5];
        for (int w = 1; w < 4; w++) {
            r0 = fminf(r0, red[w][0]); r1 = fminf(r1, red[w][1]); r2 = fminf(r2, red[w][2]);
            r3 = fmaxf(r3, red[w][3]); r4 = fmaxf(r4, red[w][4]); r5 = fmaxf(r5, red[w][5]);
        }
        unsigned* slot = ws + MM_OFF + (unsigned)((blockIdx.x + blockIdx.y * 49) & 63) * 16;
        atomicMax(slot + 0, fkey(-r0));   // min x  (as max of key(-x))
        atomicMax(slot + 1, fkey(-r1));
        atomicMax(slot + 2, fkey(-r2));
        atomicMax(slot + 3, fkey(r3));    // max x
        atomicMax(slot + 4, fkey(r4));
        atomicMax(slot + 5, fkey(r5));
    }
}

// ---------------------------------------------------------------------------
// Pass C: per-frame voxel occupancy. grid 256 (2 blocks/frame) x 512 threads.
// ---------------------------------------------------------------------------
__global__ __launch_bounds__(512) void voxel_kernel(const float* __restrict__ wp,
                                                    const float* __restrict__ conf,
                                                    const float* __restrict__ pct,
                                                    unsigned* __restrict__ ws) {
    const int s = blockIdx.x >> 1;
    const int part = blockIdx.x & 1;
    const int tid = threadIdx.x;

    __shared__ unsigned bm[VWORDS];
    __shared__ float prm[4];  // pmx,pmy,pmz,vs
    for (int w = tid; w < VWORDS; w += 512) bm[w] = 0;

    if (tid < 64) {
        const unsigned* sl = ws + MM_OFF + (unsigned)tid * 16;
        unsigned k0 = sl[0], k1 = sl[1], k2 = sl[2], k3 = sl[3], k4 = sl[4], k5 = sl[5];
#pragma unroll
        for (int m = 32; m >= 1; m >>= 1) {
            k0 = max(k0, (unsigned)__shfl_xor((int)k0, m));
            k1 = max(k1, (unsigned)__shfl_xor((int)k1, m));
            k2 = max(k2, (unsigned)__shfl_xor((int)k2, m));
            k3 = max(k3, (unsigned)__shfl_xor((int)k3, m));
            k4 = max(k4, (unsigned)__shfl_xor((int)k4, m));
            k5 = max(k5, (unsigned)__shfl_xor((int)k5, m));
        }
        if (tid == 0) {
            float p0 = -funkey(k0), p1 = -funkey(k1), p2 = -funkey(k2);
            float d0 = funkey(k3) - p0, d1 = funkey(k4) - p1, d2 = funkey(k5) - p2;
            prm[0] = p0; prm[1] = p1; prm[2] = p2;
            prm[3] = fminf(d0, fminf(d1, d2)) / 20.0f;   // VOXEL_LAMBDA
        }
    }
    __syncthreads();

    const float pc = pct[s];
    const float pmx = prm[0], pmy = prm[1], pmz = prm[2], vs = prm[3];
    const size_t base = (size_t)s * HW;
    const float4* c4 = (const float4*)(conf + base);
    const float4* w4 = (const float4*)(wp + base * 3);

#pragma unroll 1
    for (int k = 0; k < 13; k++) {
        int gl = k * 512 + tid;                        // local group in half
        if (gl >= 6272) break;
        int g = part * 6272 + gl;
        float4 cf = c4[g];
        const float4* wg = w4 + (size_t)g * 3;
        float4 a = wg[0], b = wg[1], d = wg[2];
        float px[4] = {a.x, a.w, b.z, d.y};
        float py[4] = {a.y, b.x, b.w, d.z};
        float pz[4] = {a.z, b.y, d.x, d.w};
        float cc[4] = {cf.x, cf.y, cf.z, cf.w};
#pragma unroll
        for (int j = 0; j < 4; j++) {
            if (cc[j] > 0.1f && cc[j] >= pc) {
                int ix = min(max((int)floorf((px[j] - pmx) / vs), 0), GDIM - 1);
                int iy = min(max((int)floorf((py[j] - pmy) / vs), 0), GDIM - 1);
                int iz = min(max((int)floorf((pz[j] - pmz) / vs), 0), GDIM - 1);
                int vid = (ix * GDIM + iy) * GDIM + iz;
                atomicOr(&bm[vid >> 5], 1u << (vid & 31));
            }
        }
    }
    __syncthreads();

    unsigned* occ = ws + (part ? OCCB_OFF : OCCA_OFF) + (unsigned)s * VWORDS;
    for (int w = tid; w < VWORDS; w += 512) occ[w] = bm[w];
}

// ---------------------------------------------------------------------------
// Union of all frame bitmaps. grid 4 x 256, uint4-vectorized (864 uint4 total).
// ---------------------------------------------------------------------------
__global__ __launch_bounds__(256) void union_kernel(unsigned* __restrict__ ws) {
    int q = blockIdx.x * 256 + threadIdx.x;
    if (q >= VWORDS / 4) return;
    const uint4* pA = (const uint4*)(ws + OCCA_OFF);
    const uint4* pB = (const uint4*)(ws + OCCB_OFF);
    uint4 u = make_uint4(0, 0, 0, 0);
#pragma unroll 4
    for (int f = 0; f < S_FRAMES; f++) {
        uint4 a = pA[f * (VWORDS / 4) + q], b = pB[f * (VWORDS / 4) + q];
        u.x |= a.x | b.x; u.y |= a.y | b.y; u.z |= a.z | b.z; u.w |= a.w | b.w;
    }
    ((uint4*)(ws + UNI_OFF))[q] = u;
}

// ---------------------------------------------------------------------------
// Remap each frame's bitmap into compact-id space (rank within union).
// grid 128 x 256; each block redundantly scans the union for base[] (exact).
// Output zero-padded to full UWC stride so greedy1 needs no runtime guards.
// ---------------------------------------------------------------------------
__global__ __launch_bounds__(256) void remap_kernel(unsigned* __restrict__ ws) {
    const int f = blockIdx.x;
    const int tid = threadIdx.x;
    const int lane = tid & 63, wid = tid >> 6;

    __shared__ unsigned uni[VWORDS];
    __shared__ unsigned short basew[VWORDS];
    __shared__ unsigned cbm[UWC];
    __shared__ unsigned wtot[4];
    __shared__ unsigned Ush;

    for (int w = tid; w < VWORDS; w += 256) uni[w] = ws[UNI_OFF + w];
    for (int w = tid; w < (int)UWC; w += 256) cbm[w] = 0;
    __syncthreads();

    // popc prefix scan: 14 words/thread (14*256 >= 3456)
    const int w0 = tid * 14;
    unsigned chunk = 0;
#pragma unroll
    for (int j = 0; j < 14; j++) { int w = w0 + j; if (w < VWORDS) chunk += __popc(uni[w]); }
    unsigned x = chunk;
#pragma unroll
    for (int m = 1; m < 64; m <<= 1) {
        unsigned y = (unsigned)__shfl_up((int)x, m);
        if (lane >= m) x += y;
    }
    if (lane == 63) wtot[wid] = x;
    __syncthreads();
    unsigned woffv = 0;
    for (int wv = 0; wv < 4; wv++) if (wv < wid) woffv += wtot[wv];
    unsigned running = x - chunk + woffv;
#pragma unroll
    for (int j = 0; j < 14; j++) {
        int w = w0 + j;
        if (w < VWORDS) { basew[w] = (unsigned short)running; running += __popc(uni[w]); }
    }
    if (tid == 255) Ush = running;
    __syncthreads();
    const unsigned U = Ush;
    if (f == 0 && tid == 0) { ws[FLAG_OFF] = (U <= UCAP_BITS) ? 2u : 1u; ws[UW_OFF] = (U + 31) >> 5; }
    if (U > UCAP_BITS) return;   // fallback path will run

    const unsigned* pA = ws + OCCA_OFF + (unsigned)f * VWORDS;
    const unsigned* pB = ws + OCCB_OFF + (unsigned)f * VWORDS;
    for (int w = tid; w < VWORDS; w += 256) {
        unsigned v = pA[w] | pB[w];
        if (!v) continue;
        unsigned uw = uni[w], b0 = basew[w];
        while (v) {
            int b = __ffs(v) - 1; v &= v - 1;
            unsigned cid = b0 + (unsigned)__popc(uw & ((1u << b) - 1u));
            atomicOr(&cbm[cid >> 5], 1u << (cid & 31));
        }
    }
    __syncthreads();
    for (int w = tid; w < (int)UWC; w += 256) ws[CMP_OFF + (unsigned)f * UWC + w] = cbm[w];
}

// ---------------------------------------------------------------------------
// Compact greedy: ONE block x 1024 threads, thread = (frame f=tid>>3, slice
// sl=tid&7). occ streamed from L1/L2 via uint4 loads each iteration (no
// per-thread persistent array => no scratch spill). Covered bitmap in LDS;
// owners of `best` fold disjoint words. 3 barriers/iter, zero global sync.
// ---------------------------------------------------------------------------
__global__ __launch_bounds__(1024) void greedy1_kernel(unsigned* __restrict__ ws,
                                                       float* __restrict__ out) {
    if (ws[FLAG_OFF] != 2u) return;
    const int tid = threadIdx.x;
    const int f = tid >> 3, sl = tid & 7;
    const unsigned UW = ws[UW_OFF];               // <= 512
    const int Q = (int)((UW + 31) >> 5);          // uint4 per slice; 32Q words >= UW
    const uint4* my4 = (const uint4*)(ws + CMP_OFF + (unsigned)f * UWC) + sl * Q;

    __shared__ unsigned cov[UWC];
    __shared__ int gains[S_FRAMES];
    __shared__ unsigned bestsh;

    for (int w = tid; w < (int)UWC; w += 1024) cov[w] = 0u;
    bool selF = false;
    int best = -1;
    __syncthreads();

    for (int it = 0; it < KSEL; it++) {
        if (best >= 0 && f == best) {             // owners fold cov (disjoint words)
            const uint4* b4 = (const uint4*)(ws + CMP_OFF + (unsigned)best * UWC) + sl * Q;
#pragma unroll 4
            for (int j = 0; j < Q; j++) {
                uint4 o = b4[j];
                int w = (sl * Q + j) * 4;
                cov[w] |= o.x; cov[w + 1] |= o.y; cov[w + 2] |= o.z; cov[w + 3] |= o.w;
            }
        }
        __syncthreads();                          // B1: cov updated
        int g = 0;
#pragma unroll 4
        for (int j = 0; j < Q; j++) {
            uint4 o = my4[j];
            int w = (sl * Q + j) * 4;
            g += __popc(o.x & ~cov[w]) + __popc(o.y & ~cov[w + 1])
               + __popc(o.z & ~cov[w + 2]) + __popc(o.w & ~cov[w + 3]);
        }
        g += __shfl_xor(g, 1); g += __shfl_xor(g, 2); g += __shfl_xor(g, 4);
        if (sl == 0) gains[f] = selF ? -1 : g;
        __syncthreads();                          // B2: gains ready
        if (tid < 64) {
            int g1 = gains[tid], g2 = gains[tid + 64];
            // key: max gain, then smallest s (jnp.argmax first-max tie-break)
            unsigned k1 = (g1 < 0) ? 0u : (((unsigned)g1 << 7) | (unsigned)(127 - tid));
            unsigned k2 = (g2 < 0) ? 0u : (((unsigned)g2 << 7) | (unsigned)(63 - tid));
            unsigned k = max(k1, k2);
#pragma unroll
            for (int m = 32; m >= 1; m >>= 1) k = max(k, (unsigned)__shfl_xor((int)k, m));
            if (tid == 0) {
                bestsh = k;
                out[it] = (float)(127 - (int)(k & 127u));
                out[KSEL + it] = (float)(k >> 7);
            }
        }
        __syncthreads();                          // B3: best visible
        best = 127 - (int)(bestsh & 127u);
        if (f == best) selF = true;
    }

    // total coverage: fold last best, popc over cov (f==0 group spans all words)
    if (f == best) {
        const uint4* b4 = (const uint4*)(ws + CMP_OFF + (unsigned)best * UWC) + sl * Q;
#pragma unroll 4
        for (int j = 0; j < Q; j++) {
            uint4 o = b4[j];
            int w = (sl * Q + j) * 4;
            cov[w] |= o.x; cov[w + 1] |= o.y; cov[w + 2] |= o.z; cov[w + 3] |= o.w;
        }
    }
    __syncthreads();
    if (f == 0) {
        int t = 0;
#pragma unroll 4
        for (int j = 0; j < Q; j++) {
            int w = (sl * Q + j) * 4;
            t += __popc(cov[w]) + __popc(cov[w + 1]) + __popc(cov[w + 2]) + __popc(cov[w + 3]);
        }
        t += __shfl_xor(t, 1); t += __shfl_xor(t, 2); t += __shfl_xor(t, 4);
        if (sl == 0) out[2 * KSEL] = (float)t;
    }
}

// ---------------------------------------------------------------------------
// Fallback greedy (only if U > UCAP_BITS): 16 blocks x 1024, slot all-gather.
// ---------------------------------------------------------------------------
__global__ __launch_bounds__(1024) void greedy_kernel(unsigned* __restrict__ ws,
                                                      float* __restrict__ out) {
    if (ws[FLAG_OFF] == 2u) return;
    const int b = blockIdx.x;
    const int tid = threadIdx.x;
    const int lane = tid & 63, wid = tid >> 6;
    const unsigned* pA = ws + OCCA_OFF;
    const unsigned* pB = ws + OCCB_OFF;
    unsigned* slots = ws + SLOT_OFF;         // slot(b,it) = b*32 + it

    unsigned occ[FPB][GW], cov[GW];
#pragma unroll
    for (int k = 0; k < GW; k++) cov[k] = 0u;
#pragma unroll
    for (int j = 0; j < FPB; j++) {
        unsigned f = (unsigned)(b * FPB + j);
#pragma unroll
        for (int k = 0; k < GW; k++) {
            int w = tid + k * 1024;
            occ[j][k] = (w < VWORDS) ? (pA[f * VWORDS + w] | pB[f * VWORDS + w]) : 0u;
        }
    }

    __shared__ int part[16][FPB];
    __shared__ unsigned bbc;
    unsigned selMask = 0;
    int best = -1;

    for (int it = 0; it < KSEL; it++) {
        if (best >= 0) {
            const unsigned* bA = pA + (unsigned)best * VWORDS;
            const unsigned* bB = pB + (unsigned)best * VWORDS;
#pragma unroll
            for (int k = 0; k < GW; k++) {
                int w = tid + k * 1024;
                if (w < VWORDS) cov[k] |= bA[w] | bB[w];
            }
        }
#pragma unroll
        for (int j = 0; j < FPB; j++) {
            int g = 0;
#pragma unroll
            for (int k = 0; k < GW; k++) g += __popc(occ[j][k] & ~cov[k]);
#pragma unroll
            for (int m = 32; m >= 1; m >>= 1) g += __shfl_xor(g, m);
            if (lane == 0) part[wid][j] = g;
        }
        __syncthreads();
        if (wid == 0) {
            unsigned key = 0;
            if (lane < FPB) {
                int g = 0;
#pragma unroll
                for (int w = 0; w < 16; w++) g += part[w][lane];
                int f = b * FPB + lane;
                key = ((selMask >> lane) & 1u) ? 0u
                    : (((unsigned)g << 7) | (unsigned)(127 - f));
            }
#pragma unroll
            for (int m = 4; m >= 1; m >>= 1) key = max(key, (unsigned)__shfl_xor((int)key, m));
            if (lane == 0)
                __hip_atomic_store(&slots[b * 32 + it], key | 0x80000000u,
                                   __ATOMIC_RELAXED, __HIP_MEMORY_SCOPE_AGENT);
            unsigned p = 0;
            if (lane < GBLK) {
                unsigned v;
                do {
                    v = __hip_atomic_load(&slots[lane * 32 + it],
                                          __ATOMIC_RELAXED, __HIP_MEMORY_SCOPE_AGENT);
                } while (!(v & 0x80000000u));
                p = v & 0x7fffffffu;
            }
#pragma unroll
            for (int m = 8; m >= 1; m >>= 1) p = max(p, (unsigned)__shfl_xor((int)p, m));
            if (lane == 0) bbc = p;
        }
        __syncthreads();
        unsigned kk = bbc;
        best = 127 - (int)(kk & 127u);
        if (best >= b * FPB && best < (b + 1) * FPB) selMask |= 1u << (best - b * FPB);
        if (b == 0 && tid == 0) {
            out[it] = (float)best;
            out[KSEL + it] = (float)(kk >> 7);
        }
        __syncthreads();
    }

    if (b == 0) {
        const unsigned* bA = pA + (unsigned)best * VWORDS;
        const unsigned* bB = pB + (unsigned)best * VWORDS;
        int t = 0;
#pragma unroll
        for (int k = 0; k < GW; k++) {
            int w = tid + k * 1024;
            if (w < VWORDS) t += __popc(cov[k] | bA[w] | bB[w]);
        }
#pragma unroll
        for (int m = 32; m >= 1; m >>= 1) t += __shfl_xor(t, m);
        if (lane == 0) part[wid][0] = t;
        __syncthreads();
        if (tid == 0) {
            int tt = 0;
            for (int w = 0; w < 16; w++) tt += part[w][0];
            out[2 * KSEL] = (float)tt;
        }
    }
}

extern "C" void kernel_launch(void* const* d_in, const int* in_sizes, int n_in,
                              void* d_out, int out_size, void* d_ws, size_t ws_size,
                              hipStream_t stream) {
    const float* wp   = (const float*)d_in[2];  // world_points [1,S,H,W,3]
    const float* conf = (const float*)d_in[3];  // world_points_conf [1,S,H,W]
    float* out = (float*)d_out;
    unsigned* ws = (unsigned*)d_ws;

    // zero only the control region: key slots + minmax slots
    hipMemsetAsync(ws + ZERO_OFF, 0, (size_t)ZERO_WORDS * 4, stream);

    float* pct = (float*)(ws + PCT_OFF);
    pct_kernel<<<128, 1024, 0, stream>>>(conf, pct);
    minmax_kernel<<<dim3(49, 128), 256, 0, stream>>>(wp, conf, pct, ws);
    voxel_kernel<<<256, 512, 0, stream>>>(wp, conf, pct, ws);
    union_kernel<<<4, 256, 0, stream>>>(ws);
    remap_kernel<<<128, 256, 0, stream>>>(ws);
    greedy1_kernel<<<1, 1024, 0, stream>>>(ws, out);
    greedy_kernel<<<GBLK, 1024, 0, stream>>>(ws, out);
}

// Round 8
// 240.193 us; speedup vs baseline: 1.1669x; 1.1066x over previous
//
#include <hip/hip_runtime.h>
#include <hip/hip_bf16.h>
#include <cstdint>

// Problem constants
#define S_FRAMES 128
#define HW       50176            // 224*224
#define NGRP     12544            // HW/4 float4 groups per frame
#define GDIM     48
#define VWORDS   3456             // 48^3 / 32 bits
#define NBINS    4096
#define CAP      512
#define KSEL     16

// fallback greedy decomposition
#define GBLK     16               // blocks
#define FPB      8                // frames per block
#define GW       4                // occ words per thread (tid + k*1024)

// compact greedy
#define UWC      512u             // compact stride (words) per frame, zero-padded
#define UCAP_BITS 16384u          // max compact bits handled by greedy1
#define RQ       9                // register-tier uint4 per slice (288 words)

// workspace layout (in 32-bit words)
#define OCCA_OFF  0u                          // 128 * 3456 words (part 0 bitmaps)
#define OCCB_OFF  (128u*3456u)                // 442368: part 1 bitmaps
#define SLOT_OFF  (2u*128u*3456u)             // 884736: 16 blocks x 32 words (own lines)
#define MM_OFF    (SLOT_OFF + 512u)           // 64 slots x 16 words (64B each)
#define PCT_OFF   (MM_OFF + 64u*16u)          // 128 floats
#define FLAG_OFF  (PCT_OFF + 128u)            // 1=fallback, 2=compact
#define UW_OFF    (FLAG_OFF + 1u)             // compact words per frame
#define UNI_OFF   (FLAG_OFF + 16u)            // union bitmap, 3456 words
#define CMP_OFF   (UNI_OFF + VWORDS)          // 128 x 512 compact bitmaps (16B aligned)
#define ZERO_OFF  SLOT_OFF
#define ZERO_WORDS (CMP_OFF - SLOT_OFF)       // slots + mm + pct + flag + UNI

__device__ __forceinline__ unsigned fkey(float f) {
    unsigned u = __float_as_uint(f);
    return (u & 0x80000000u) ? ~u : (u | 0x80000000u);
}
__device__ __forceinline__ float funkey(unsigned k) {
    unsigned u = (k & 0x80000000u) ? (k & 0x7fffffffu) : ~k;
    return __uint_as_float(u);
}

// ---------------------------------------------------------------------------
// Pass A: exact per-frame median (jnp.quantile 0.5 linear) via histogram select
// ---------------------------------------------------------------------------
__global__ __launch_bounds__(1024) void pct_kernel(const float* __restrict__ conf,
                                                   float* __restrict__ pct) {
    const int s = blockIdx.x;
    const int tid = threadIdx.x;
    const int lane = tid & 63, wid = tid >> 6;
    const float4* c4 = (const float4*)(conf + (size_t)s * HW);

    __shared__ unsigned hist[NBINS];
    __shared__ unsigned wtot[16];
    __shared__ unsigned woff[16];
    __shared__ float    list[CAP];
    __shared__ unsigned cnt;
    __shared__ int      rbin[2];
    __shared__ unsigned rcum[2];
    __shared__ float    ab[2];

    for (int b = tid; b < NBINS; b += 1024) hist[b] = 0;
    if (tid == 0) cnt = 0;
    __syncthreads();

    for (int g = tid; g < NGRP; g += 1024) {
        float4 v = c4[g];
        int b0 = min(max((int)(v.x * 4096.0f), 0), NBINS - 1);
        int b1 = min(max((int)(v.y * 4096.0f), 0), NBINS - 1);
        int b2 = min(max((int)(v.z * 4096.0f), 0), NBINS - 1);
        int b3 = min(max((int)(v.w * 4096.0f), 0), NBINS - 1);
        atomicAdd(&hist[b0], 1u); atomicAdd(&hist[b1], 1u);
        atomicAdd(&hist[b2], 1u); atomicAdd(&hist[b3], 1u);
    }
    __syncthreads();

    unsigned chunk = hist[tid * 4] + hist[tid * 4 + 1] + hist[tid * 4 + 2] + hist[tid * 4 + 3];
    unsigned x = chunk;
#pragma unroll
    for (int m = 1; m < 64; m <<= 1) {
        unsigned y = (unsigned)__shfl_up((int)x, m);
        if (lane >= m) x += y;
    }
    if (lane == 63) wtot[wid] = x;
    __syncthreads();
    if (tid < 16) {
        unsigned acc = 0;
        for (int w = 0; w < tid; w++) acc += wtot[w];
        woff[tid] = acc;
    }
    __syncthreads();
    unsigned excl = x - chunk + woff[wid];

    const unsigned R0 = 25087u, R1 = 25088u;  // 0.5*(50176-1) = 25087.5
#pragma unroll
    for (int r = 0; r < 2; r++) {
        unsigned rr = r ? R1 : R0;
        if (rr >= excl && rr < excl + chunk) {
            unsigned cum = excl;
            for (int j = 0; j < 4; j++) {
                unsigned h = hist[tid * 4 + j];
                if (rr < cum + h) { rbin[r] = tid * 4 + j; rcum[r] = cum; break; }
                cum += h;
            }
        }
    }
    __syncthreads();

    const int blo = rbin[0], bhi = rbin[1];
    const unsigned cumLo = rcum[0];

    for (int g = tid; g < NGRP; g += 1024) {
        float4 v = c4[g];
        float vv[4] = {v.x, v.y, v.z, v.w};
#pragma unroll
        for (int j = 0; j < 4; j++) {
            int b = min(max((int)(vv[j] * 4096.0f), 0), NBINS - 1);
            if (b >= blo && b <= bhi) {
                unsigned pos = atomicAdd(&cnt, 1u);
                if (pos < CAP) list[pos] = vv[j];
            }
        }
    }
    __syncthreads();

    const int n = (int)min(cnt, (unsigned)CAP);
    const int r0 = (int)(R0 - cumLo), r1 = (int)(R1 - cumLo);
    for (int e = tid; e < n; e += 1024) {
        float xx = list[e];
        int rank = 0;
        for (int j = 0; j < n; j++) {
            float y = list[j];
            rank += (y < xx) || (y == xx && j < e);   // stable rank
        }
        if (rank == r0) ab[0] = xx;
        if (rank == r1) ab[1] = xx;
    }
    __syncthreads();
    if (tid == 0) pct[s] = 0.5f * ab[0] + 0.5f * ab[1];
}

// ---------------------------------------------------------------------------
// Pass B: global min/max over valid points. grid (49,128) x 256, 4 pts/thread.
// ---------------------------------------------------------------------------
__global__ __launch_bounds__(256) void minmax_kernel(const float* __restrict__ wp,
                                                     const float* __restrict__ conf,
                                                     const float* __restrict__ pct,
                                                     unsigned* __restrict__ ws) {
    const int s = blockIdx.y;
    const int tid = threadIdx.x;
    const int gidx = blockIdx.x * 256 + tid;        // [0, 12544)
    const float pc = pct[s];
    const size_t base = (size_t)s * HW;

    const float4 cf = ((const float4*)(conf + base))[gidx];
    const float4* wp4 = (const float4*)(wp + base * 3) + (size_t)gidx * 3;
    const float4 a = wp4[0], b = wp4[1], d = wp4[2];

    const float BIG = 3.402823466e38f;
    float mnx = BIG, mny = BIG, mnz = BIG;
    float mxx = -BIG, mxy = -BIG, mxz = -BIG;

    float px[4] = {a.x, a.w, b.z, d.y};
    float py[4] = {a.y, b.x, b.w, d.z};
    float pz[4] = {a.z, b.y, d.x, d.w};
    float cc[4] = {cf.x, cf.y, cf.z, cf.w};
#pragma unroll
    for (int j = 0; j < 4; j++) {
        bool v = (cc[j] > 0.1f) && (cc[j] >= pc);
        float x = v ? px[j] : BIG, y = v ? py[j] : BIG, z = v ? pz[j] : BIG;
        mnx = fminf(mnx, x); mny = fminf(mny, y); mnz = fminf(mnz, z);
        x = v ? px[j] : -BIG; y = v ? py[j] : -BIG; z = v ? pz[j] : -BIG;
        mxx = fmaxf(mxx, x); mxy = fmaxf(mxy, y); mxz = fmaxf(mxz, z);
    }
#pragma unroll
    for (int m = 32; m >= 1; m >>= 1) {
        mnx = fminf(mnx, __shfl_xor(mnx, m)); mny = fminf(mny, __shfl_xor(mny, m));
        mnz = fminf(mnz, __shfl_xor(mnz, m));
        mxx = fmaxf(mxx, __shfl_xor(mxx, m)); mxy = fmaxf(mxy, __shfl_xor(mxy, m));
        mxz = fmaxf(mxz, __shfl_xor(mxz, m));
    }
    __shared__ float red[4][6];
    if ((tid & 63) == 0) {
        int w = tid >> 6;
        red[w][0] = mnx; red[w][1] = mny; red[w][2] = mnz;
        red[w][3] = mxx; red[w][4] = mxy; red[w][5] = mxz;
    }
    __syncthreads();
    if (tid == 0) {
        float r0 = red[0][0], r1 = red[0][1], r2 = red[0][2];
        float r3 = red[0][3], r4 = red[0][4], r5 = red[0][5];
        for (int w = 1; w < 4; w++) {
            r0 = fminf(r0, red[w][0]); r1 = fminf(r1, red[w][1]); r2 = fminf(r2, red[w][2]);
            r3 = fmaxf(r3, red[w][3]); r4 = fmaxf(r4, red[w][4]); r5 = fmaxf(r5, red[w][5]);
        }
        unsigned* slot = ws + MM_OFF + (unsigned)((blockIdx.x + blockIdx.y * 49) & 63) * 16;
        atomicMax(slot + 0, fkey(-r0));   // min x  (as max of key(-x))
        atomicMax(slot + 1, fkey(-r1));
        atomicMax(slot + 2, fkey(-r2));
        atomicMax(slot + 3, fkey(r3));    // max x
        atomicMax(slot + 4, fkey(r4));
        atomicMax(slot + 5, fkey(r5));
    }
}

// ---------------------------------------------------------------------------
// Pass C: per-frame voxel occupancy + fused union. grid 256 (2/frame) x 512.
// Block stores its half-frame plane AND atomicOrs nonzero words into UNI.
// ---------------------------------------------------------------------------
__global__ __launch_bounds__(512) void voxel_kernel(const float* __restrict__ wp,
                                                    const float* __restrict__ conf,
                                                    const float* __restrict__ pct,
                                                    unsigned* __restrict__ ws) {
    const int s = blockIdx.x >> 1;
    const int part = blockIdx.x & 1;
    const int tid = threadIdx.x;

    __shared__ unsigned bm[VWORDS];
    __shared__ float prm[4];  // pmx,pmy,pmz,vs
    for (int w = tid; w < VWORDS; w += 512) bm[w] = 0;

    if (tid < 64) {
        const unsigned* sl = ws + MM_OFF + (unsigned)tid * 16;
        unsigned k0 = sl[0], k1 = sl[1], k2 = sl[2], k3 = sl[3], k4 = sl[4], k5 = sl[5];
#pragma unroll
        for (int m = 32; m >= 1; m >>= 1) {
            k0 = max(k0, (unsigned)__shfl_xor((int)k0, m));
            k1 = max(k1, (unsigned)__shfl_xor((int)k1, m));
            k2 = max(k2, (unsigned)__shfl_xor((int)k2, m));
            k3 = max(k3, (unsigned)__shfl_xor((int)k3, m));
            k4 = max(k4, (unsigned)__shfl_xor((int)k4, m));
            k5 = max(k5, (unsigned)__shfl_xor((int)k5, m));
        }
        if (tid == 0) {
            float p0 = -funkey(k0), p1 = -funkey(k1), p2 = -funkey(k2);
            float d0 = funkey(k3) - p0, d1 = funkey(k4) - p1, d2 = funkey(k5) - p2;
            prm[0] = p0; prm[1] = p1; prm[2] = p2;
            prm[3] = fminf(d0, fminf(d1, d2)) / 20.0f;   // VOXEL_LAMBDA
        }
    }
    __syncthreads();

    const float pc = pct[s];
    const float pmx = prm[0], pmy = prm[1], pmz = prm[2], vs = prm[3];
    const size_t base = (size_t)s * HW;
    const float4* c4 = (const float4*)(conf + base);
    const float4* w4 = (const float4*)(wp + base * 3);

#pragma unroll 1
    for (int k = 0; k < 13; k++) {
        int gl = k * 512 + tid;                        // local group in half
        if (gl >= 6272) break;
        int g = part * 6272 + gl;
        float4 cf = c4[g];
        const float4* wg = w4 + (size_t)g * 3;
        float4 a = wg[0], b = wg[1], d = wg[2];
        float px[4] = {a.x, a.w, b.z, d.y};
        float py[4] = {a.y, b.x, b.w, d.z};
        float pz[4] = {a.z, b.y, d.x, d.w};
        float cc[4] = {cf.x, cf.y, cf.z, cf.w};
#pragma unroll
        for (int j = 0; j < 4; j++) {
            if (cc[j] > 0.1f && cc[j] >= pc) {
                int ix = min(max((int)floorf((px[j] - pmx) / vs), 0), GDIM - 1);
                int iy = min(max((int)floorf((py[j] - pmy) / vs), 0), GDIM - 1);
                int iz = min(max((int)floorf((pz[j] - pmz) / vs), 0), GDIM - 1);
                int vid = (ix * GDIM + iy) * GDIM + iz;
                atomicOr(&bm[vid >> 5], 1u << (vid & 31));
            }
        }
    }
    __syncthreads();

    unsigned* occ = ws + (part ? OCCB_OFF : OCCA_OFF) + (unsigned)s * VWORDS;
    for (int w = tid; w < VWORDS; w += 512) {
        unsigned v = bm[w];
        occ[w] = v;
        if (v) atomicOr(&ws[UNI_OFF + w], v);   // fused union (UNI pre-zeroed)
    }
}

// ---------------------------------------------------------------------------
// Remap each frame's bitmap into compact-id space (rank within union).
// grid 128 x 256; each block redundantly scans the union for base[] (exact).
// Output zero-padded to full UWC stride so greedy1 needs no runtime guards.
// ---------------------------------------------------------------------------
__global__ __launch_bounds__(256) void remap_kernel(unsigned* __restrict__ ws) {
    const int f = blockIdx.x;
    const int tid = threadIdx.x;
    const int lane = tid & 63, wid = tid >> 6;

    __shared__ unsigned uni[VWORDS];
    __shared__ unsigned short basew[VWORDS];
    __shared__ unsigned cbm[UWC];
    __shared__ unsigned wtot[4];
    __shared__ unsigned Ush;

    for (int w = tid; w < VWORDS; w += 256) uni[w] = ws[UNI_OFF + w];
    for (int w = tid; w < (int)UWC; w += 256) cbm[w] = 0;
    __syncthreads();

    // popc prefix scan: 14 words/thread (14*256 >= 3456)
    const int w0 = tid * 14;
    unsigned chunk = 0;
#pragma unroll
    for (int j = 0; j < 14; j++) { int w = w0 + j; if (w < VWORDS) chunk += __popc(uni[w]); }
    unsigned x = chunk;
#pragma unroll
    for (int m = 1; m < 64; m <<= 1) {
        unsigned y = (unsigned)__shfl_up((int)x, m);
        if (lane >= m) x += y;
    }
    if (lane == 63) wtot[wid] = x;
    __syncthreads();
    unsigned woffv = 0;
    for (int wv = 0; wv < 4; wv++) if (wv < wid) woffv += wtot[wv];
    unsigned running = x - chunk + woffv;
#pragma unroll
    for (int j = 0; j < 14; j++) {
        int w = w0 + j;
        if (w < VWORDS) { basew[w] = (unsigned short)running; running += __popc(uni[w]); }
    }
    if (tid == 255) Ush = running;
    __syncthreads();
    const unsigned U = Ush;
    if (f == 0 && tid == 0) { ws[FLAG_OFF] = (U <= UCAP_BITS) ? 2u : 1u; ws[UW_OFF] = (U + 31) >> 5; }
    if (U > UCAP_BITS) return;   // fallback path will run

    const unsigned* pA = ws + OCCA_OFF + (unsigned)f * VWORDS;
    const unsigned* pB = ws + OCCB_OFF + (unsigned)f * VWORDS;
    for (int w = tid; w < VWORDS; w += 256) {
        unsigned v = pA[w] | pB[w];
        if (!v) continue;
        unsigned uw = uni[w], b0 = basew[w];
        while (v) {
            int b = __ffs(v) - 1; v &= v - 1;
            unsigned cid = b0 + (unsigned)__popc(uw & ((1u << b) - 1u));
            atomicOr(&cbm[cid >> 5], 1u << (cid & 31));
        }
    }
    __syncthreads();
    for (int w = tid; w < (int)UWC; w += 256) ws[CMP_OFF + (unsigned)f * UWC + w] = cbm[w];
}

// ---------------------------------------------------------------------------
// Compact greedy: ONE block x 1024 threads, thread = (frame f=tid>>3, slice
// sl=tid&7). Register tier (UW<=288): slice in 9 uint4 = 36 VGPRs, gain loop
// is pure regs+LDS. Streaming tier (UW<=512): uint4 loads from L2 each iter.
// Covered bitmap in LDS; owners of `best` fold disjoint words. 3 barriers/iter.
// ---------------------------------------------------------------------------
__global__ __launch_bounds__(1024, 1) void greedy1_kernel(unsigned* __restrict__ ws,
                                                          float* __restrict__ out) {
    if (ws[FLAG_OFF] != 2u) return;
    const int tid = threadIdx.x;
    const int f = tid >> 3, sl = tid & 7;
    const unsigned UW = ws[UW_OFF];               // <= 512

    __shared__ unsigned cov[UWC];
    __shared__ int gains[S_FRAMES];
    __shared__ unsigned bestsh;

    for (int w = tid; w < (int)UWC; w += 1024) cov[w] = 0u;
    bool selF = false;
    int best = -1;

    if (UW <= 32u * RQ) {
        // ---------------- register tier ----------------
        uint4 occw[RQ];
        const uint4* my4 = (const uint4*)(ws + CMP_OFF + (unsigned)f * UWC) + sl * RQ;
#pragma unroll
        for (int j = 0; j < RQ; j++) occw[j] = my4[j];
        __syncthreads();

        for (int it = 0; it < KSEL; it++) {
            if (best >= 0 && f == best) {         // owners fold cov from regs
#pragma unroll
                for (int j = 0; j < RQ; j++) {
                    int w = (sl * RQ + j) * 4;
                    cov[w] |= occw[j].x; cov[w + 1] |= occw[j].y;
                    cov[w + 2] |= occw[j].z; cov[w + 3] |= occw[j].w;
                }
            }
            __syncthreads();                      // B1: cov updated
            int g = 0;
#pragma unroll
            for (int j = 0; j < RQ; j++) {
                int w = (sl * RQ + j) * 4;
                g += __popc(occw[j].x & ~cov[w]) + __popc(occw[j].y & ~cov[w + 1])
                   + __popc(occw[j].z & ~cov[w + 2]) + __popc(occw[j].w & ~cov[w + 3]);
            }
            g += __shfl_xor(g, 1); g += __shfl_xor(g, 2); g += __shfl_xor(g, 4);
            if (sl == 0) gains[f] = selF ? -1 : g;
            __syncthreads();                      // B2: gains ready
            if (tid < 64) {
                int g1 = gains[tid], g2 = gains[tid + 64];
                unsigned k1 = (g1 < 0) ? 0u : (((unsigned)g1 << 7) | (unsigned)(127 - tid));
                unsigned k2 = (g2 < 0) ? 0u : (((unsigned)g2 << 7) | (unsigned)(63 - tid));
                unsigned k = max(k1, k2);
#pragma unroll
                for (int m = 32; m >= 1; m >>= 1) k = max(k, (unsigned)__shfl_xor((int)k, m));
                if (tid == 0) {
                    bestsh = k;
                    out[it] = (float)(127 - (int)(k & 127u));
                    out[KSEL + it] = (float)(k >> 7);
                }
            }
            __syncthreads();                      // B3: best visible
            best = 127 - (int)(bestsh & 127u);
            if (f == best) selF = true;
        }
        if (f == best) {
#pragma unroll
            for (int j = 0; j < RQ; j++) {
                int w = (sl * RQ + j) * 4;
                cov[w] |= occw[j].x; cov[w + 1] |= occw[j].y;
                cov[w + 2] |= occw[j].z; cov[w + 3] |= occw[j].w;
            }
        }
        __syncthreads();
        if (f == 0) {
            int t = 0;
#pragma unroll
            for (int j = 0; j < RQ; j++) {
                int w = (sl * RQ + j) * 4;
                t += __popc(cov[w]) + __popc(cov[w + 1]) + __popc(cov[w + 2]) + __popc(cov[w + 3]);
            }
            t += __shfl_xor(t, 1); t += __shfl_xor(t, 2); t += __shfl_xor(t, 4);
            if (sl == 0) out[2 * KSEL] = (float)t;
        }
    } else {
        // ---------------- streaming tier ----------------
        const int Q = (int)((UW + 31) >> 5);      // uint4 per slice
        const uint4* my4 = (const uint4*)(ws + CMP_OFF + (unsigned)f * UWC) + sl * Q;
        __syncthreads();

        for (int it = 0; it < KSEL; it++) {
            if (best >= 0 && f == best) {
                const uint4* b4 = (const uint4*)(ws + CMP_OFF + (unsigned)best * UWC) + sl * Q;
#pragma unroll 4
                for (int j = 0; j < Q; j++) {
                    uint4 o = b4[j];
                    int w = (sl * Q + j) * 4;
                    cov[w] |= o.x; cov[w + 1] |= o.y; cov[w + 2] |= o.z; cov[w + 3] |= o.w;
                }
            }
            __syncthreads();                      // B1
            int g = 0;
#pragma unroll 4
            for (int j = 0; j < Q; j++) {
                uint4 o = my4[j];
                int w = (sl * Q + j) * 4;
                g += __popc(o.x & ~cov[w]) + __popc(o.y & ~cov[w + 1])
                   + __popc(o.z & ~cov[w + 2]) + __popc(o.w & ~cov[w + 3]);
            }
            g += __shfl_xor(g, 1); g += __shfl_xor(g, 2); g += __shfl_xor(g, 4);
            if (sl == 0) gains[f] = selF ? -1 : g;
            __syncthreads();                      // B2
            if (tid < 64) {
                int g1 = gains[tid], g2 = gains[tid + 64];
                unsigned k1 = (g1 < 0) ? 0u : (((unsigned)g1 << 7) | (unsigned)(127 - tid));
                unsigned k2 = (g2 < 0) ? 0u : (((unsigned)g2 << 7) | (unsigned)(63 - tid));
                unsigned k = max(k1, k2);
#pragma unroll
                for (int m = 32; m >= 1; m >>= 1) k = max(k, (unsigned)__shfl_xor((int)k, m));
                if (tid == 0) {
                    bestsh = k;
                    out[it] = (float)(127 - (int)(k & 127u));
                    out[KSEL + it] = (float)(k >> 7);
                }
            }
            __syncthreads();                      // B3
            best = 127 - (int)(bestsh & 127u);
            if (f == best) selF = true;
        }
        if (f == best) {
            const uint4* b4 = (const uint4*)(ws + CMP_OFF + (unsigned)best * UWC) + sl * Q;
#pragma unroll 4
            for (int j = 0; j < Q; j++) {
                uint4 o = b4[j];
                int w = (sl * Q + j) * 4;
                cov[w] |= o.x; cov[w + 1] |= o.y; cov[w + 2] |= o.z; cov[w + 3] |= o.w;
            }
        }
        __syncthreads();
        if (f == 0) {
            int t = 0;
#pragma unroll 4
            for (int j = 0; j < Q; j++) {
                int w = (sl * Q + j) * 4;
                t += __popc(cov[w]) + __popc(cov[w + 1]) + __popc(cov[w + 2]) + __popc(cov[w + 3]);
            }
            t += __shfl_xor(t, 1); t += __shfl_xor(t, 2); t += __shfl_xor(t, 4);
            if (sl == 0) out[2 * KSEL] = (float)t;
        }
    }
}

// ---------------------------------------------------------------------------
// Fallback greedy (only if U > UCAP_BITS): 16 blocks x 1024, slot all-gather.
// ---------------------------------------------------------------------------
__global__ __launch_bounds__(1024) void greedy_kernel(unsigned* __restrict__ ws,
                                                      float* __restrict__ out) {
    if (ws[FLAG_OFF] == 2u) return;
    const int b = blockIdx.x;
    const int tid = threadIdx.x;
    const int lane = tid & 63, wid = tid >> 6;
    const unsigned* pA = ws + OCCA_OFF;
    const unsigned* pB = ws + OCCB_OFF;
    unsigned* slots = ws + SLOT_OFF;         // slot(b,it) = b*32 + it

    unsigned occ[FPB][GW], cov[GW];
#pragma unroll
    for (int k = 0; k < GW; k++) cov[k] = 0u;
#pragma unroll
    for (int j = 0; j < FPB; j++) {
        unsigned f = (unsigned)(b * FPB + j);
#pragma unroll
        for (int k = 0; k < GW; k++) {
            int w = tid + k * 1024;
            occ[j][k] = (w < VWORDS) ? (pA[f * VWORDS + w] | pB[f * VWORDS + w]) : 0u;
        }
    }

    __shared__ int part[16][FPB];
    __shared__ unsigned bbc;
    unsigned selMask = 0;
    int best = -1;

    for (int it = 0; it < KSEL; it++) {
        if (best >= 0) {
            const unsigned* bA = pA + (unsigned)best * VWORDS;
            const unsigned* bB = pB + (unsigned)best * VWORDS;
#pragma unroll
            for (int k = 0; k < GW; k++) {
                int w = tid + k * 1024;
                if (w < VWORDS) cov[k] |= bA[w] | bB[w];
            }
        }
#pragma unroll
        for (int j = 0; j < FPB; j++) {
            int g = 0;
#pragma unroll
            for (int k = 0; k < GW; k++) g += __popc(occ[j][k] & ~cov[k]);
#pragma unroll
            for (int m = 32; m >= 1; m >>= 1) g += __shfl_xor(g, m);
            if (lane == 0) part[wid][j] = g;
        }
        __syncthreads();
        if (wid == 0) {
            unsigned key = 0;
            if (lane < FPB) {
                int g = 0;
#pragma unroll
                for (int w = 0; w < 16; w++) g += part[w][lane];
                int f = b * FPB + lane;
                key = ((selMask >> lane) & 1u) ? 0u
                    : (((unsigned)g << 7) | (unsigned)(127 - f));
            }
#pragma unroll
            for (int m = 4; m >= 1; m >>= 1) key = max(key, (unsigned)__shfl_xor((int)key, m));
            if (lane == 0)
                __hip_atomic_store(&slots[b * 32 + it], key | 0x80000000u,
                                   __ATOMIC_RELAXED, __HIP_MEMORY_SCOPE_AGENT);
            unsigned p = 0;
            if (lane < GBLK) {
                unsigned v;
                do {
                    v = __hip_atomic_load(&slots[lane * 32 + it],
                                          __ATOMIC_RELAXED, __HIP_MEMORY_SCOPE_AGENT);
                } while (!(v & 0x80000000u));
                p = v & 0x7fffffffu;
            }
#pragma unroll
            for (int m = 8; m >= 1; m >>= 1) p = max(p, (unsigned)__shfl_xor((int)p, m));
            if (lane == 0) bbc = p;
        }
        __syncthreads();
        unsigned kk = bbc;
        best = 127 - (int)(kk & 127u);
        if (best >= b * FPB && best < (b + 1) * FPB) selMask |= 1u << (best - b * FPB);
        if (b == 0 && tid == 0) {
            out[it] = (float)best;
            out[KSEL + it] = (float)(kk >> 7);
        }
        __syncthreads();
    }

    if (b == 0) {
        const unsigned* bA = pA + (unsigned)best * VWORDS;
        const unsigned* bB = pB + (unsigned)best * VWORDS;
        int t = 0;
#pragma unroll
        for (int k = 0; k < GW; k++) {
            int w = tid + k * 1024;
            if (w < VWORDS) t += __popc(cov[k] | bA[w] | bB[w]);
        }
#pragma unroll
        for (int m = 32; m >= 1; m >>= 1) t += __shfl_xor(t, m);
        if (lane == 0) part[wid][0] = t;
        __syncthreads();
        if (tid == 0) {
            int tt = 0;
            for (int w = 0; w < 16; w++) tt += part[w][0];
            out[2 * KSEL] = (float)tt;
        }
    }
}

extern "C" void kernel_launch(void* const* d_in, const int* in_sizes, int n_in,
                              void* d_out, int out_size, void* d_ws, size_t ws_size,
                              hipStream_t stream) {
    const float* wp   = (const float*)d_in[2];  // world_points [1,S,H,W,3]
    const float* conf = (const float*)d_in[3];  // world_points_conf [1,S,H,W]
    float* out = (float*)d_out;
    unsigned* ws = (unsigned*)d_ws;

    // zero control region: key slots + mm slots + pct + flag + UNI (one memset)
    hipMemsetAsync(ws + ZERO_OFF, 0, (size_t)ZERO_WORDS * 4, stream);

    float* pct = (float*)(ws + PCT_OFF);
    pct_kernel<<<128, 1024, 0, stream>>>(conf, pct);
    minmax_kernel<<<dim3(49, 128), 256, 0, stream>>>(wp, conf, pct, ws);
    voxel_kernel<<<256, 512, 0, stream>>>(wp, conf, pct, ws);
    remap_kernel<<<128, 256, 0, stream>>>(ws);
    greedy1_kernel<<<1, 1024, 0, stream>>>(ws, out);
    greedy_kernel<<<GBLK, 1024, 0, stream>>>(ws, out);
}

// Round 9
// 225.319 us; speedup vs baseline: 1.2439x; 1.0660x over previous
//
#include <hip/hip_runtime.h>
#include <hip/hip_bf16.h>
#include <cstdint>

// Problem constants
#define S_FRAMES 128
#define HW       50176            // 224*224
#define NGRP     12544            // HW/4 float4 groups per frame
#define GDIM     48
#define VWORDS   3456             // 48^3 / 32 bits
#define NBINS    4096
#define CAP      512
#define KSEL     16

// compact greedy
#define UWC      512u             // compact stride (words) per frame, zero-padded
#define UCAP_BITS 16384u          // max compact bits handled (streaming tier)
#define RQ       9                // register-tier uint4 per slice (288 words)

// workspace layout (in 32-bit words)
#define OCCA_OFF  0u                          // 128 * 3456 words (part 0 bitmaps)
#define OCCB_OFF  (128u*3456u)                // 442368: part 1 bitmaps
#define MM_OFF    (2u*128u*3456u)             // 884736: 64 slots x 16 words (64B each)
#define PCT_OFF   (MM_OFF + 64u*16u)          // 128 floats
#define FLAG_OFF  (PCT_OFF + 128u)            // flag (2=compact), +1 = UW
#define UW_OFF    (FLAG_OFF + 1u)
#define UNI_OFF   (FLAG_OFF + 16u)            // union bitmap, 3456 words
#define CMP_OFF   (UNI_OFF + VWORDS)          // 128 x 512 compact bitmaps (16B aligned)
#define VB_OFF    (CMP_OFF + 128u*UWC)        // 128 x 1568 words valid nibbles
// zero ranges handled inside pct_kernel: [MM_OFF,+1024) and [FLAG_OFF,+3472)
#define ZR1_N     1024u
#define ZR2_N     (16u + VWORDS)              // 3472
#define ZR_TOT    (ZR1_N + ZR2_N)             // 4496

__device__ __forceinline__ unsigned fkey(float f) {
    unsigned u = __float_as_uint(f);
    return (u & 0x80000000u) ? ~u : (u | 0x80000000u);
}
__device__ __forceinline__ float funkey(unsigned k) {
    unsigned u = (k & 0x80000000u) ? (k & 0x7fffffffu) : ~k;
    return __uint_as_float(u);
}

// ---------------------------------------------------------------------------
// Pass A: exact per-frame median (jnp.quantile 0.5 linear) via histogram select
// + folded control-region zeroing (disjoint 36-word chunk per block; pct never
// reads these regions, consumers launch after this kernel completes).
// ---------------------------------------------------------------------------
__global__ __launch_bounds__(1024) void pct_kernel(const float* __restrict__ conf,
                                                   float* __restrict__ pct,
                                                   unsigned* __restrict__ ws) {
    const int s = blockIdx.x;
    const int tid = threadIdx.x;
    const int lane = tid & 63, wid = tid >> 6;
    const float4* c4 = (const float4*)(conf + (size_t)s * HW);

    // zero 36 control words per block (128*36 = 4608 >= 4496)
    if (tid < 36) {
        unsigned idx = (unsigned)s * 36u + tid;
        if (idx < ZR_TOT) {
            if (idx < ZR1_N) ws[MM_OFF + idx] = 0u;
            else             ws[FLAG_OFF + (idx - ZR1_N)] = 0u;
        }
    }

    __shared__ unsigned hist[NBINS];
    __shared__ unsigned wtot[16];
    __shared__ unsigned woff[16];
    __shared__ float    list[CAP];
    __shared__ unsigned cnt;
    __shared__ int      rbin[2];
    __shared__ unsigned rcum[2];
    __shared__ float    ab[2];

    for (int b = tid; b < NBINS; b += 1024) hist[b] = 0;
    if (tid == 0) cnt = 0;
    __syncthreads();

    for (int g = tid; g < NGRP; g += 1024) {
        float4 v = c4[g];
        int b0 = min(max((int)(v.x * 4096.0f), 0), NBINS - 1);
        int b1 = min(max((int)(v.y * 4096.0f), 0), NBINS - 1);
        int b2 = min(max((int)(v.z * 4096.0f), 0), NBINS - 1);
        int b3 = min(max((int)(v.w * 4096.0f), 0), NBINS - 1);
        atomicAdd(&hist[b0], 1u); atomicAdd(&hist[b1], 1u);
        atomicAdd(&hist[b2], 1u); atomicAdd(&hist[b3], 1u);
    }
    __syncthreads();

    unsigned chunk = hist[tid * 4] + hist[tid * 4 + 1] + hist[tid * 4 + 2] + hist[tid * 4 + 3];
    unsigned x = chunk;
#pragma unroll
    for (int m = 1; m < 64; m <<= 1) {
        unsigned y = (unsigned)__shfl_up((int)x, m);
        if (lane >= m) x += y;
    }
    if (lane == 63) wtot[wid] = x;
    __syncthreads();
    if (tid < 16) {
        unsigned acc = 0;
        for (int w = 0; w < tid; w++) acc += wtot[w];
        woff[tid] = acc;
    }
    __syncthreads();
    unsigned excl = x - chunk + woff[wid];

    const unsigned R0 = 25087u, R1 = 25088u;  // 0.5*(50176-1) = 25087.5
#pragma unroll
    for (int r = 0; r < 2; r++) {
        unsigned rr = r ? R1 : R0;
        if (rr >= excl && rr < excl + chunk) {
            unsigned cum = excl;
            for (int j = 0; j < 4; j++) {
                unsigned h = hist[tid * 4 + j];
                if (rr < cum + h) { rbin[r] = tid * 4 + j; rcum[r] = cum; break; }
                cum += h;
            }
        }
    }
    __syncthreads();

    const int blo = rbin[0], bhi = rbin[1];
    const unsigned cumLo = rcum[0];

    for (int g = tid; g < NGRP; g += 1024) {
        float4 v = c4[g];
        float vv[4] = {v.x, v.y, v.z, v.w};
#pragma unroll
        for (int j = 0; j < 4; j++) {
            int b = min(max((int)(vv[j] * 4096.0f), 0), NBINS - 1);
            if (b >= blo && b <= bhi) {
                unsigned pos = atomicAdd(&cnt, 1u);
                if (pos < CAP) list[pos] = vv[j];
            }
        }
    }
    __syncthreads();

    const int n = (int)min(cnt, (unsigned)CAP);
    const int r0 = (int)(R0 - cumLo), r1 = (int)(R1 - cumLo);
    for (int e = tid; e < n; e += 1024) {
        float xx = list[e];
        int rank = 0;
        for (int j = 0; j < n; j++) {
            float y = list[j];
            rank += (y < xx) || (y == xx && j < e);   // stable rank
        }
        if (rank == r0) ab[0] = xx;
        if (rank == r1) ab[1] = xx;
    }
    __syncthreads();
    if (tid == 0) pct[s] = 0.5f * ab[0] + 0.5f * ab[1];
}

// ---------------------------------------------------------------------------
// Pass B: global min/max over valid points + emit packed valid nibbles.
// grid (49,128) x 256, 4 pts/thread. Nibble g: bit j = valid(point 4g+j).
// ---------------------------------------------------------------------------
__global__ __launch_bounds__(256) void minmax_kernel(const float* __restrict__ wp,
                                                     const float* __restrict__ conf,
                                                     const float* __restrict__ pct,
                                                     unsigned* __restrict__ ws) {
    const int s = blockIdx.y;
    const int tid = threadIdx.x;
    const int gidx = blockIdx.x * 256 + tid;        // [0, 12544)
    const float pc = pct[s];
    const size_t base = (size_t)s * HW;

    const float4 cf = ((const float4*)(conf + base))[gidx];
    const float4* wp4 = (const float4*)(wp + base * 3) + (size_t)gidx * 3;
    const float4 a = wp4[0], b = wp4[1], d = wp4[2];

    const float BIG = 3.402823466e38f;
    float mnx = BIG, mny = BIG, mnz = BIG;
    float mxx = -BIG, mxy = -BIG, mxz = -BIG;

    float px[4] = {a.x, a.w, b.z, d.y};
    float py[4] = {a.y, b.x, b.w, d.z};
    float pz[4] = {a.z, b.y, d.x, d.w};
    float cc[4] = {cf.x, cf.y, cf.z, cf.w};
    unsigned nib = 0;
#pragma unroll
    for (int j = 0; j < 4; j++) {
        bool v = (cc[j] > 0.1f) && (cc[j] >= pc);
        nib |= (v ? 1u : 0u) << j;
        float x = v ? px[j] : BIG, y = v ? py[j] : BIG, z = v ? pz[j] : BIG;
        mnx = fminf(mnx, x); mny = fminf(mny, y); mnz = fminf(mnz, z);
        x = v ? px[j] : -BIG; y = v ? py[j] : -BIG; z = v ? pz[j] : -BIG;
        mxx = fmaxf(mxx, x); mxy = fmaxf(mxy, y); mxz = fmaxf(mxz, z);
    }

    // pack 8 nibbles/word in LDS, store 32 words (256 groups) per block
    __shared__ unsigned vbw[32];
    if (tid < 32) vbw[tid] = 0;
    __syncthreads();
    if (nib) atomicOr(&vbw[tid >> 3], nib << ((tid & 7) * 4));

#pragma unroll
    for (int m = 32; m >= 1; m >>= 1) {
        mnx = fminf(mnx, __shfl_xor(mnx, m)); mny = fminf(mny, __shfl_xor(mny, m));
        mnz = fminf(mnz, __shfl_xor(mnz, m));
        mxx = fmaxf(mxx, __shfl_xor(mxx, m)); mxy = fmaxf(mxy, __shfl_xor(mxy, m));
        mxz = fmaxf(mxz, __shfl_xor(mxz, m));
    }
    __shared__ float red[4][6];
    if ((tid & 63) == 0) {
        int w = tid >> 6;
        red[w][0] = mnx; red[w][1] = mny; red[w][2] = mnz;
        red[w][3] = mxx; red[w][4] = mxy; red[w][5] = mxz;
    }
    __syncthreads();
    if (tid < 32)
        ws[VB_OFF + (unsigned)s * 1568u + (unsigned)blockIdx.x * 32u + tid] = vbw[tid];
    if (tid == 0) {
        float r0 = red[0][0], r1 = red[0][1], r2 = red[0][2];
        float r3 = red[0][3], r4 = red[0][4], r5 = red[0][5];
        for (int w = 1; w < 4; w++) {
            r0 = fminf(r0, red[w][0]); r1 = fminf(r1, red[w][1]); r2 = fminf(r2, red[w][2]);
            r3 = fmaxf(r3, red[w][3]); r4 = fmaxf(r4, red[w][4]); r5 = fmaxf(r5, red[w][5]);
        }
        unsigned* slot = ws + MM_OFF + (unsigned)((blockIdx.x + blockIdx.y * 49) & 63) * 16;
        atomicMax(slot + 0, fkey(-r0));   // min x  (as max of key(-x))
        atomicMax(slot + 1, fkey(-r1));
        atomicMax(slot + 2, fkey(-r2));
        atomicMax(slot + 3, fkey(r3));    // max x
        atomicMax(slot + 4, fkey(r4));
        atomicMax(slot + 5, fkey(r5));
    }
}

// ---------------------------------------------------------------------------
// Pass C: per-frame voxel occupancy + fused union. grid 256 (2/frame) x 512.
// Consumes valid nibbles (no conf re-read). Stores half-frame plane; ORs
// nonzero words into UNI.
// ---------------------------------------------------------------------------
__global__ __launch_bounds__(512) void voxel_kernel(const float* __restrict__ wp,
                                                    unsigned* __restrict__ ws) {
    const int s = blockIdx.x >> 1;
    const int part = blockIdx.x & 1;
    const int tid = threadIdx.x;

    __shared__ unsigned bm[VWORDS];
    __shared__ float prm[4];  // pmx,pmy,pmz,vs
    for (int w = tid; w < VWORDS; w += 512) bm[w] = 0;

    if (tid < 64) {
        const unsigned* sl = ws + MM_OFF + (unsigned)tid * 16;
        unsigned k0 = sl[0], k1 = sl[1], k2 = sl[2], k3 = sl[3], k4 = sl[4], k5 = sl[5];
#pragma unroll
        for (int m = 32; m >= 1; m >>= 1) {
            k0 = max(k0, (unsigned)__shfl_xor((int)k0, m));
            k1 = max(k1, (unsigned)__shfl_xor((int)k1, m));
            k2 = max(k2, (unsigned)__shfl_xor((int)k2, m));
            k3 = max(k3, (unsigned)__shfl_xor((int)k3, m));
            k4 = max(k4, (unsigned)__shfl_xor((int)k4, m));
            k5 = max(k5, (unsigned)__shfl_xor((int)k5, m));
        }
        if (tid == 0) {
            float p0 = -funkey(k0), p1 = -funkey(k1), p2 = -funkey(k2);
            float d0 = funkey(k3) - p0, d1 = funkey(k4) - p1, d2 = funkey(k5) - p2;
            prm[0] = p0; prm[1] = p1; prm[2] = p2;
            prm[3] = fminf(d0, fminf(d1, d2)) / 20.0f;   // VOXEL_LAMBDA
        }
    }
    __syncthreads();

    const float pmx = prm[0], pmy = prm[1], pmz = prm[2], vs = prm[3];
    const size_t base = (size_t)s * HW;
    const float4* w4 = (const float4*)(wp + base * 3);
    const unsigned* vb = ws + VB_OFF + (unsigned)s * 1568u;

#pragma unroll 1
    for (int k = 0; k < 13; k++) {
        int gl = k * 512 + tid;                        // local group in half
        if (gl >= 6272) break;
        int g = part * 6272 + gl;
        unsigned nib = (vb[g >> 3] >> ((g & 7) * 4)) & 0xFu;
        if (!nib) continue;
        const float4* wg = w4 + (size_t)g * 3;
        float4 a = wg[0], b = wg[1], d = wg[2];
        float px[4] = {a.x, a.w, b.z, d.y};
        float py[4] = {a.y, b.x, b.w, d.z};
        float pz[4] = {a.z, b.y, d.x, d.w};
#pragma unroll
        for (int j = 0; j < 4; j++) {
            if ((nib >> j) & 1u) {
                int ix = min(max((int)floorf((px[j] - pmx) / vs), 0), GDIM - 1);
                int iy = min(max((int)floorf((py[j] - pmy) / vs), 0), GDIM - 1);
                int iz = min(max((int)floorf((pz[j] - pmz) / vs), 0), GDIM - 1);
                int vid = (ix * GDIM + iy) * GDIM + iz;
                atomicOr(&bm[vid >> 5], 1u << (vid & 31));
            }
        }
    }
    __syncthreads();

    unsigned* occ = ws + (part ? OCCB_OFF : OCCA_OFF) + (unsigned)s * VWORDS;
    for (int w = tid; w < VWORDS; w += 512) {
        unsigned v = bm[w];
        occ[w] = v;
        if (v) atomicOr(&ws[UNI_OFF + w], v);   // fused union (UNI pre-zeroed)
    }
}

// ---------------------------------------------------------------------------
// Remap each frame's bitmap into compact-id space (rank within union).
// grid 128 x 1024; each block redundantly scans the union for base[] (exact).
// Output zero-padded to full UWC stride.
// ---------------------------------------------------------------------------
__global__ __launch_bounds__(1024) void remap_kernel(unsigned* __restrict__ ws) {
    const int f = blockIdx.x;
    const int tid = threadIdx.x;
    const int lane = tid & 63, wid = tid >> 6;

    __shared__ unsigned uni[VWORDS];
    __shared__ unsigned short basew[VWORDS];
    __shared__ unsigned cbm[UWC];
    __shared__ unsigned wtot[16];
    __shared__ unsigned woff[16];
    __shared__ unsigned Ush;

    for (int w = tid; w < VWORDS; w += 1024) uni[w] = ws[UNI_OFF + w];
    for (int w = tid; w < (int)UWC; w += 1024) cbm[w] = 0;
    __syncthreads();

    // popc prefix scan: 4 words/thread (4*1024 >= 3456)
    const int w0 = tid * 4;
    unsigned chunk = 0;
#pragma unroll
    for (int j = 0; j < 4; j++) { int w = w0 + j; if (w < VWORDS) chunk += __popc(uni[w]); }
    unsigned x = chunk;
#pragma unroll
    for (int m = 1; m < 64; m <<= 1) {
        unsigned y = (unsigned)__shfl_up((int)x, m);
        if (lane >= m) x += y;
    }
    if (lane == 63) wtot[wid] = x;
    __syncthreads();
    if (tid < 16) {
        unsigned acc = 0;
        for (int w = 0; w < tid; w++) acc += wtot[w];
        woff[tid] = acc;
    }
    __syncthreads();
    unsigned running = x - chunk + woff[wid];
#pragma unroll
    for (int j = 0; j < 4; j++) {
        int w = w0 + j;
        if (w < VWORDS) { basew[w] = (unsigned short)running; running += __popc(uni[w]); }
    }
    if (tid == 1023) Ush = running;
    __syncthreads();
    const unsigned U = Ush;
    if (f == 0 && tid == 0) { ws[FLAG_OFF] = (U <= UCAP_BITS) ? 2u : 1u; ws[UW_OFF] = (U + 31) >> 5; }
    if (U > UCAP_BITS) return;

    const unsigned* pA = ws + OCCA_OFF + (unsigned)f * VWORDS;
    const unsigned* pB = ws + OCCB_OFF + (unsigned)f * VWORDS;
    for (int w = tid; w < VWORDS; w += 1024) {
        unsigned v = pA[w] | pB[w];
        if (!v) continue;
        unsigned uw = uni[w], b0 = basew[w];
        while (v) {
            int b = __ffs(v) - 1; v &= v - 1;
            unsigned cid = b0 + (unsigned)__popc(uw & ((1u << b) - 1u));
            atomicOr(&cbm[cid >> 5], 1u << (cid & 31));
        }
    }
    __syncthreads();
    for (int w = tid; w < (int)UWC; w += 1024) ws[CMP_OFF + (unsigned)f * UWC + w] = cbm[w];
}

// ---------------------------------------------------------------------------
// Compact greedy: ONE block x 1024 threads, thread = (frame f=tid>>3, slice
// sl=tid&7). Register tier (UW<=288): slice in 9 uint4 = 36 VGPRs. Streaming
// tier (UW<=512): uint4 loads from L2 each iter. Covered bitmap in LDS;
// owners of `best` fold disjoint words. 3 barriers/iter, zero global sync.
// ---------------------------------------------------------------------------
__global__ __launch_bounds__(1024, 1) void greedy1_kernel(unsigned* __restrict__ ws,
                                                          float* __restrict__ out) {
    if (ws[FLAG_OFF] != 2u) return;
    const int tid = threadIdx.x;
    const int f = tid >> 3, sl = tid & 7;
    const unsigned UW = ws[UW_OFF];               // <= 512

    __shared__ unsigned cov[UWC];
    __shared__ int gains[S_FRAMES];
    __shared__ unsigned bestsh;

    for (int w = tid; w < (int)UWC; w += 1024) cov[w] = 0u;
    bool selF = false;
    int best = -1;

    if (UW <= 32u * RQ) {
        // ---------------- register tier ----------------
        uint4 occw[RQ];
        const uint4* my4 = (const uint4*)(ws + CMP_OFF + (unsigned)f * UWC) + sl * RQ;
#pragma unroll
        for (int j = 0; j < RQ; j++) occw[j] = my4[j];
        __syncthreads();

        for (int it = 0; it < KSEL; it++) {
            if (best >= 0 && f == best) {         // owners fold cov from regs
#pragma unroll
                for (int j = 0; j < RQ; j++) {
                    int w = (sl * RQ + j) * 4;
                    cov[w] |= occw[j].x; cov[w + 1] |= occw[j].y;
                    cov[w + 2] |= occw[j].z; cov[w + 3] |= occw[j].w;
                }
            }
            __syncthreads();                      // B1: cov updated
            int g = 0;
#pragma unroll
            for (int j = 0; j < RQ; j++) {
                int w = (sl * RQ + j) * 4;
                g += __popc(occw[j].x & ~cov[w]) + __popc(occw[j].y & ~cov[w + 1])
                   + __popc(occw[j].z & ~cov[w + 2]) + __popc(occw[j].w & ~cov[w + 3]);
            }
            g += __shfl_xor(g, 1); g += __shfl_xor(g, 2); g += __shfl_xor(g, 4);
            if (sl == 0) gains[f] = selF ? -1 : g;
            __syncthreads();                      // B2: gains ready
            if (tid < 64) {
                int g1 = gains[tid], g2 = gains[tid + 64];
                unsigned k1 = (g1 < 0) ? 0u : (((unsigned)g1 << 7) | (unsigned)(127 - tid));
                unsigned k2 = (g2 < 0) ? 0u : (((unsigned)g2 << 7) | (unsigned)(63 - tid));
                unsigned k = max(k1, k2);
#pragma unroll
                for (int m = 32; m >= 1; m >>= 1) k = max(k, (unsigned)__shfl_xor((int)k, m));
                if (tid == 0) {
                    bestsh = k;
                    out[it] = (float)(127 - (int)(k & 127u));
                    out[KSEL + it] = (float)(k >> 7);
                }
            }
            __syncthreads();                      // B3: best visible
            best = 127 - (int)(bestsh & 127u);
            if (f == best) selF = true;
        }
        if (f == best) {
#pragma unroll
            for (int j = 0; j < RQ; j++) {
                int w = (sl * RQ + j) * 4;
                cov[w] |= occw[j].x; cov[w + 1] |= occw[j].y;
                cov[w + 2] |= occw[j].z; cov[w + 3] |= occw[j].w;
            }
        }
        __syncthreads();
        if (f == 0) {
            int t = 0;
#pragma unroll
            for (int j = 0; j < RQ; j++) {
                int w = (sl * RQ + j) * 4;
                t += __popc(cov[w]) + __popc(cov[w + 1]) + __popc(cov[w + 2]) + __popc(cov[w + 3]);
            }
            t += __shfl_xor(t, 1); t += __shfl_xor(t, 2); t += __shfl_xor(t, 4);
            if (sl == 0) out[2 * KSEL] = (float)t;
        }
    } else {
        // ---------------- streaming tier ----------------
        const int Q = (int)((UW + 31) >> 5);      // uint4 per slice
        const uint4* my4 = (const uint4*)(ws + CMP_OFF + (unsigned)f * UWC) + sl * Q;
        __syncthreads();

        for (int it = 0; it < KSEL; it++) {
            if (best >= 0 && f == best) {
                const uint4* b4 = (const uint4*)(ws + CMP_OFF + (unsigned)best * UWC) + sl * Q;
#pragma unroll 4
                for (int j = 0; j < Q; j++) {
                    uint4 o = b4[j];
                    int w = (sl * Q + j) * 4;
                    cov[w] |= o.x; cov[w + 1] |= o.y; cov[w + 2] |= o.z; cov[w + 3] |= o.w;
                }
            }
            __syncthreads();                      // B1
            int g = 0;
#pragma unroll 4
            for (int j = 0; j < Q; j++) {
                uint4 o = my4[j];
                int w = (sl * Q + j) * 4;
                g += __popc(o.x & ~cov[w]) + __popc(o.y & ~cov[w + 1])
                   + __popc(o.z & ~cov[w + 2]) + __popc(o.w & ~cov[w + 3]);
            }
            g += __shfl_xor(g, 1); g += __shfl_xor(g, 2); g += __shfl_xor(g, 4);
            if (sl == 0) gains[f] = selF ? -1 : g;
            __syncthreads();                      // B2
            if (tid < 64) {
                int g1 = gains[tid], g2 = gains[tid + 64];
                unsigned k1 = (g1 < 0) ? 0u : (((unsigned)g1 << 7) | (unsigned)(127 - tid));
                unsigned k2 = (g2 < 0) ? 0u : (((unsigned)g2 << 7) | (unsigned)(63 - tid));
                unsigned k = max(k1, k2);
#pragma unroll
                for (int m = 32; m >= 1; m >>= 1) k = max(k, (unsigned)__shfl_xor((int)k, m));
                if (tid == 0) {
                    bestsh = k;
                    out[it] = (float)(127 - (int)(k & 127u));
                    out[KSEL + it] = (float)(k >> 7);
                }
            }
            __syncthreads();                      // B3
            best = 127 - (int)(bestsh & 127u);
            if (f == best) selF = true;
        }
        if (f == best) {
            const uint4* b4 = (const uint4*)(ws + CMP_OFF + (unsigned)best * UWC) + sl * Q;
#pragma unroll 4
            for (int j = 0; j < Q; j++) {
                uint4 o = b4[j];
                int w = (sl * Q + j) * 4;
                cov[w] |= o.x; cov[w + 1] |= o.y; cov[w + 2] |= o.z; cov[w + 3] |= o.w;
            }
        }
        __syncthreads();
        if (f == 0) {
            int t = 0;
#pragma unroll 4
            for (int j = 0; j < Q; j++) {
                int w = (sl * Q + j) * 4;
                t += __popc(cov[w]) + __popc(cov[w + 1]) + __popc(cov[w + 2]) + __popc(cov[w + 3]);
            }
            t += __shfl_xor(t, 1); t += __shfl_xor(t, 2); t += __shfl_xor(t, 4);
            if (sl == 0) out[2 * KSEL] = (float)t;
        }
    }
}

extern "C" void kernel_launch(void* const* d_in, const int* in_sizes, int n_in,
                              void* d_out, int out_size, void* d_ws, size_t ws_size,
                              hipStream_t stream) {
    const float* wp   = (const float*)d_in[2];  // world_points [1,S,H,W,3]
    const float* conf = (const float*)d_in[3];  // world_points_conf [1,S,H,W]
    float* out = (float*)d_out;
    unsigned* ws = (unsigned*)d_ws;

    float* pct = (float*)(ws + PCT_OFF);
    pct_kernel<<<128, 1024, 0, stream>>>(conf, pct, ws);
    minmax_kernel<<<dim3(49, 128), 256, 0, stream>>>(wp, conf, pct, ws);
    voxel_kernel<<<256, 512, 0, stream>>>(wp, ws);
    remap_kernel<<<128, 1024, 0, stream>>>(ws);
    greedy1_kernel<<<1, 1024, 0, stream>>>(ws, out);
}